// Round 1
// baseline (637.811 us; speedup 1.0000x reference)
//
#include <hip/hip_runtime.h>
#include <math.h>

#define KN   20000
#define IN_  50000
#define DD   128
#define NN   70000
#define E1N  320000
#define E2N  640000

__device__ __forceinline__ float wred_max(float v) {
#pragma unroll
  for (int o = 32; o > 0; o >>= 1) v = fmaxf(v, __shfl_xor(v, o, 64));
  return v;
}
__device__ __forceinline__ float wred_sum(float v) {
#pragma unroll
  for (int o = 32; o > 0; o >>= 1) v += __shfl_xor(v, o, 64);
  return v;
}

// z[rows x 128] = concat(h1,h2)[row] @ W (+ bias). row < split -> h1, else h2[row-split].
// Block: 256 thr, 64 rows x 128 cols tile; thread: 4 rows x 8 cols.
// W kept in LDS transposed + xor-swizzled so ds_read_b128 along k is ~conflict-free.
__global__ __launch_bounds__(256, 2) void gemm128(
    const float* __restrict__ h1, const float* __restrict__ h2, int split,
    const float* __restrict__ W, const float* __restrict__ bias,
    float* __restrict__ z, int rows)
{
  __shared__ float Wl[128 * 128];
  const int tid = threadIdx.x;
  // store W^T swizzled: element (k,c) -> Wl[c*128 + ((k>>2)^((c>>3)&7))*4 + (k&3)]
  for (int idx = tid; idx < 16384; idx += 256) {
    int k = idx >> 7, c = idx & 127;
    Wl[c * 128 + ((((k >> 2) ^ ((c >> 3) & 7)) << 2) | (k & 3))] = W[idx];
  }
  __syncthreads();

  const int tc = tid & 15;        // col group: cols 8*tc .. 8*tc+7
  const int tr = tid >> 4;        // row group: rows 4*tr .. 4*tr+3
  const int r0 = blockIdx.x * 64 + tr * 4;

  const float* hp[4];
  int rowv[4];
#pragma unroll
  for (int i = 0; i < 4; ++i) {
    int r = r0 + i;
    rowv[i] = r;
    int rc = (r < rows) ? r : (rows - 1);
    hp[i] = (rc < split) ? (h1 + (size_t)rc * 128) : (h2 + (size_t)(rc - split) * 128);
  }

  float acc[4][8];
#pragma unroll
  for (int i = 0; i < 4; ++i)
#pragma unroll
    for (int j = 0; j < 8; ++j) acc[i][j] = 0.f;

  const int swz = tc & 7;
  for (int k0 = 0; k0 < 128; k0 += 4) {
    float4 hv[4];
#pragma unroll
    for (int i = 0; i < 4; ++i) hv[i] = *(const float4*)(hp[i] + k0);
    const int kk = (((k0 >> 2) ^ swz) << 2);
    float4 wv[8];
#pragma unroll
    for (int j = 0; j < 8; ++j)
      wv[j] = *(const float4*)&Wl[(8 * tc + j) * 128 + kk];
#pragma unroll
    for (int i = 0; i < 4; ++i)
#pragma unroll
      for (int j = 0; j < 8; ++j)
        acc[i][j] += hv[i].x * wv[j].x + hv[i].y * wv[j].y +
                     hv[i].z * wv[j].z + hv[i].w * wv[j].w;
  }

  float b[8];
  if (bias) {
    float4 b0 = *(const float4*)(bias + 8 * tc);
    float4 b1v = *(const float4*)(bias + 8 * tc + 4);
    b[0]=b0.x; b[1]=b0.y; b[2]=b0.z; b[3]=b0.w;
    b[4]=b1v.x; b[5]=b1v.y; b[6]=b1v.z; b[7]=b1v.w;
  } else {
#pragma unroll
    for (int j = 0; j < 8; ++j) b[j] = 0.f;
  }

#pragma unroll
  for (int i = 0; i < 4; ++i) {
    if (rowv[i] < rows) {
      float4 o0 = make_float4(acc[i][0]+b[0], acc[i][1]+b[1], acc[i][2]+b[2], acc[i][3]+b[3]);
      float4 o1 = make_float4(acc[i][4]+b[4], acc[i][5]+b[5], acc[i][6]+b[6], acc[i][7]+b[7]);
      float* zp = z + (size_t)rowv[i] * 128 + 8 * tc;
      *(float4*)zp = o0;
      *(float4*)(zp + 4) = o1;
    }
  }
}

// per-row dot with a[:128] and a[128:], one wave per row
__global__ __launch_bounds__(256) void row_dots(
    const float* __restrict__ z, const float* __restrict__ a,
    float* __restrict__ ssrc, float* __restrict__ sdst, int n)
{
  int w = (blockIdx.x * 256 + threadIdx.x) >> 6;
  int lane = threadIdx.x & 63;
  if (w >= n) return;
  float2 zv = ((const float2*)(z + (size_t)w * 128))[lane];
  float2 al = ((const float2*)a)[lane];
  float2 ah = ((const float2*)(a + 128))[lane];
  float v1 = zv.x * al.x + zv.y * al.y;
  float v2 = zv.x * ah.x + zv.y * ah.y;
  v1 = wred_sum(v1);
  v2 = wred_sum(v2);
  if (lane == 0) { ssrc[w] = v1; sdst[w] = v2; }
}

__global__ __launch_bounds__(256) void count_edges(
    const int* __restrict__ ddst, const int* __restrict__ kedst, const int* __restrict__ ekdst,
    int* __restrict__ cnt_dir, int* __restrict__ cnt_ke, int* __restrict__ cnt_ek)
{
  int i = blockIdx.x * 256 + threadIdx.x;
  if (i < E1N) {
    atomicAdd(&cnt_dir[ddst[i]], 1);
  } else if (i < E1N + E2N) {
    int d = kedst[i - E1N];
    if (d >= IN_) atomicAdd(&cnt_ke[d - IN_], 1);
  } else if (i < E1N + 2 * E2N) {
    int d = ekdst[i - E1N - E2N];
    if (d < IN_) atomicAdd(&cnt_ek[d], 1);
  }
}

// 3 independent single-block exclusive scans (one per blockIdx.x)
__global__ __launch_bounds__(1024) void scan3(
    const int* __restrict__ c0, int* __restrict__ o0, int n0,
    const int* __restrict__ c1, int* __restrict__ o1, int n1,
    const int* __restrict__ c2, int* __restrict__ o2, int n2)
{
  const int* cnt; int* off; int n;
  if (blockIdx.x == 0)      { cnt = c0; off = o0; n = n0; }
  else if (blockIdx.x == 1) { cnt = c1; off = o1; n = n1; }
  else                      { cnt = c2; off = o2; n = n2; }

  __shared__ int lb[1024];
  const int tid = threadIdx.x;
  int carry = 0;
  for (int base = 0; base < n; base += 4096) {
    int i0 = base + tid * 4;
    int v[4];
#pragma unroll
    for (int j = 0; j < 4; ++j) v[j] = (i0 + j < n) ? cnt[i0 + j] : 0;
    int s = v[0] + v[1] + v[2] + v[3];
    lb[tid] = s;
    __syncthreads();
    for (int st = 1; st < 1024; st <<= 1) {
      int t = (tid >= st) ? lb[tid - st] : 0;
      __syncthreads();
      lb[tid] += t;
      __syncthreads();
    }
    int excl = lb[tid] - s;
    int total = lb[1023];
    int run = carry + excl;
#pragma unroll
    for (int j = 0; j < 4; ++j) {
      if (i0 + j < n) off[i0 + j] = run;
      run += v[j];
    }
    carry += total;
    __syncthreads();
  }
  if (tid == 0) off[n] = carry;
}

__global__ __launch_bounds__(256) void fill_edges(
    const int* __restrict__ ddst, const int* __restrict__ kedst, const int* __restrict__ ekdst,
    const int* __restrict__ off_dir, int* __restrict__ cur_dir, int* __restrict__ el_dir,
    const int* __restrict__ off_ke,  int* __restrict__ cur_ke,  int* __restrict__ el_ke,
    const int* __restrict__ off_ek,  int* __restrict__ cur_ek,  int* __restrict__ el_ek)
{
  int i = blockIdx.x * 256 + threadIdx.x;
  if (i < E1N) {
    int d = ddst[i];
    int pos = off_dir[d] + atomicAdd(&cur_dir[d], 1);
    el_dir[pos] = i;
  } else if (i < E1N + E2N) {
    int e = i - E1N;
    int d = kedst[e];
    if (d >= IN_) {
      int seg = d - IN_;
      int pos = off_ke[seg] + atomicAdd(&cur_ke[seg], 1);
      el_ke[pos] = e;
    }
  } else if (i < E1N + 2 * E2N) {
    int e = i - E1N - E2N;
    int d = ekdst[e];
    if (d < IN_) {
      int pos = off_ek[d] + atomicAdd(&cur_ek[d], 1);
      el_ek[pos] = e;
    }
  }
}

// One wave per destination segment; softmax-weighted gather of z[src] rows.
__global__ __launch_bounds__(256) void gat_gather(
    const int* __restrict__ off_dir, const int* __restrict__ el_dir, const int* __restrict__ dir_src,
    const float* __restrict__ sds, const float* __restrict__ sdd,
    const float* __restrict__ z_dir, float* __restrict__ A,
    const int* __restrict__ off_ke, const int* __restrict__ el_ke, const int* __restrict__ ke_src,
    const float* __restrict__ sks, const float* __restrict__ skd,
    const float* __restrict__ z_ke, float* __restrict__ Bm,
    const int* __restrict__ off_ek, const int* __restrict__ el_ek, const int* __restrict__ ek_src,
    const float* __restrict__ ses, const float* __restrict__ sed,
    const float* __restrict__ z_ek, float* __restrict__ Cout)
{
  int w = (blockIdx.x * 256 + threadIdx.x) >> 6;
  int lane = threadIdx.x & 63;
  const int *off, *el, *srcA;
  const float *sS, *sD, *z;
  float* out;
  int seg, node;
  if (w < KN)            { seg = w;          node = seg;        off = off_dir; el = el_dir; srcA = dir_src; sS = sds; sD = sdd; z = z_dir; out = A; }
  else if (w < 2 * KN)   { seg = w - KN;     node = seg + IN_;  off = off_ke;  el = el_ke;  srcA = ke_src;  sS = sks; sD = skd; z = z_ke;  out = Bm; }
  else if (w < 2 * KN + IN_) { seg = w - 2 * KN; node = seg;    off = off_ek;  el = el_ek;  srcA = ek_src;  sS = ses; sD = sed; z = z_ek;  out = Cout; }
  else return;

  int b = off[seg], e = off[seg + 1];
  float2 acc = make_float2(0.f, 0.f);
  if (e > b) {
    float sd = sD[node];
    float m = -INFINITY;
    for (int i = b + lane; i < e; i += 64) {
      float x = sS[srcA[el[i]]] + sd;
      x = (x > 0.f) ? x : 0.01f * x;
      m = fmaxf(m, x);
    }
    m = wred_max(m);
    float den = 0.f;
    for (int i = b + lane; i < e; i += 64) {
      float x = sS[srcA[el[i]]] + sd;
      x = (x > 0.f) ? x : 0.01f * x;
      den += __expf(x - m);
    }
    den = wred_sum(den);
    float inv = 1.f / den;
    for (int i = b; i < e; ++i) {
      int s = srcA[el[i]];
      float x = sS[s] + sd;
      x = (x > 0.f) ? x : 0.01f * x;
      float al = __expf(x - m) * inv;
      float2 zv = ((const float2*)(z + (size_t)s * 128))[lane];
      acc.x += al * zv.x;
      acc.y += al * zv.y;
    }
  }
  ((float2*)(out + (size_t)seg * 128))[lane] = acc;
}

// s[row] = sum_j tanh(T[row][j]) * w2[j]  (T already includes +b1 from gemm bias)
__global__ __launch_bounds__(256) void score_rows(
    const float* __restrict__ TA, const float* __restrict__ TB,
    const float* __restrict__ w2, float* __restrict__ s1, float* __restrict__ s2)
{
  int w = (blockIdx.x * 256 + threadIdx.x) >> 6;
  int lane = threadIdx.x & 63;
  if (w >= 2 * KN) return;
  const float* T = (w < KN) ? TA : TB;
  int row = (w < KN) ? w : w - KN;
  float2 t = ((const float2*)(T + (size_t)row * 128))[lane];
  float2 wv = ((const float2*)w2)[lane];
  float v = tanhf(t.x) * wv.x + tanhf(t.y) * wv.y;
  v = wred_sum(v);
  if (lane == 0) ((w < KN) ? s1 : s2)[row] = v;
}

__global__ __launch_bounds__(256) void combine(
    const float* __restrict__ A, const float* __restrict__ Bm,
    const float* __restrict__ s1, const float* __restrict__ s2,
    float* __restrict__ out)
{
  int i = blockIdx.x * 256 + threadIdx.x;   // float4 index
  if (i >= KN * 32) return;
  int row = i >> 5;
  float a = s1[row], b = s2[row];
  float mm = fmaxf(a, b);
  float e1 = __expf(a - mm), e2 = __expf(b - mm);
  float den = e1 + e2;
  float al = e1 / den, be = e2 / den;
  float4 av = ((const float4*)A)[i];
  float4 bv = ((const float4*)Bm)[i];
  float4 o = make_float4(al * av.x + be * bv.x, al * av.y + be * bv.y,
                         al * av.z + be * bv.z, al * av.w + be * bv.w);
  ((float4*)out)[i] = o;
}

extern "C" void kernel_launch(void* const* d_in, const int* in_sizes, int n_in,
                              void* d_out, int out_size, void* d_ws, size_t ws_size,
                              hipStream_t stream) {
  const float* kn    = (const float*)d_in[0];
  const float* ex    = (const float*)d_in[1];
  const float* W_dir = (const float*)d_in[2];
  const float* a_dir = (const float*)d_in[3];
  const float* W_ke  = (const float*)d_in[4];
  const float* a_ke  = (const float*)d_in[5];
  const float* W_ek  = (const float*)d_in[6];
  const float* a_ek  = (const float*)d_in[7];
  const float* rW1   = (const float*)d_in[8];
  const float* rb1   = (const float*)d_in[9];
  const float* rw2   = (const float*)d_in[10];
  const int* dsrc    = (const int*)d_in[11];
  const int* ddst    = (const int*)d_in[12];
  const int* kesrc   = (const int*)d_in[13];
  const int* kedst   = (const int*)d_in[14];
  const int* eksrc   = (const int*)d_in[15];
  const int* ekdst   = (const int*)d_in[16];
  float* out = (float*)d_out;

  char* p = (char*)d_ws;
  auto alloc = [&](size_t bytes) {
    char* r = p;
    p += (bytes + 255) & ~(size_t)255;
    return r;
  };
  float* z_dir = (float*)alloc((size_t)KN * 128 * 4);
  float* z_ke  = (float*)alloc((size_t)NN * 128 * 4);
  float* z_ek  = (float*)alloc((size_t)NN * 128 * 4);
  float* Am    = (float*)alloc((size_t)KN * 128 * 4);
  float* Bmat  = (float*)alloc((size_t)KN * 128 * 4);
  float* sds = (float*)alloc(KN * 4);
  float* sdd = (float*)alloc(KN * 4);
  float* sks = (float*)alloc(NN * 4);
  float* skd = (float*)alloc(NN * 4);
  float* ses = (float*)alloc(NN * 4);
  float* sed = (float*)alloc(NN * 4);
  float* s1  = (float*)alloc(KN * 4);
  float* s2  = (float*)alloc(KN * 4);
  int* cntblk  = (int*)alloc((size_t)(4 * KN + 2 * IN_) * 4);
  int* cnt_dir = cntblk;
  int* cur_dir = cntblk + KN;
  int* cnt_ke  = cntblk + 2 * KN;
  int* cur_ke  = cntblk + 3 * KN;
  int* cnt_ek  = cntblk + 4 * KN;
  int* cur_ek  = cntblk + 4 * KN + IN_;
  int* off_dir = (int*)alloc((KN + 1) * 4);
  int* off_ke  = (int*)alloc((KN + 1) * 4);
  int* off_ek  = (int*)alloc((IN_ + 1) * 4);
  int* el_dir  = (int*)alloc((size_t)E1N * 4);
  int* el_ke   = (int*)alloc((size_t)E2N * 4);
  int* el_ek   = (int*)alloc((size_t)E2N * 4);
  // reuse (stream-ordered, z_dir/z_ke dead after gat_gather):
  float* TA = z_dir;
  float* TB = z_ke;

  hipMemsetAsync(cntblk, 0, (size_t)(4 * KN + 2 * IN_) * 4, stream);

  gemm128<<<(KN + 63) / 64, 256, 0, stream>>>(kn, kn, KN, W_dir, nullptr, z_dir, KN);
  gemm128<<<(NN + 63) / 64, 256, 0, stream>>>(ex, kn, IN_, W_ke, nullptr, z_ke, NN);
  gemm128<<<(NN + 63) / 64, 256, 0, stream>>>(ex, kn, IN_, W_ek, nullptr, z_ek, NN);

  row_dots<<<(KN + 3) / 4, 256, 0, stream>>>(z_dir, a_dir, sds, sdd, KN);
  row_dots<<<(NN + 3) / 4, 256, 0, stream>>>(z_ke, a_ke, sks, skd, NN);
  row_dots<<<(NN + 3) / 4, 256, 0, stream>>>(z_ek, a_ek, ses, sed, NN);

  count_edges<<<(E1N + 2 * E2N + 255) / 256, 256, 0, stream>>>(ddst, kedst, ekdst,
                                                              cnt_dir, cnt_ke, cnt_ek);
  scan3<<<3, 1024, 0, stream>>>(cnt_dir, off_dir, KN, cnt_ke, off_ke, KN, cnt_ek, off_ek, IN_);
  fill_edges<<<(E1N + 2 * E2N + 255) / 256, 256, 0, stream>>>(
      ddst, kedst, ekdst, off_dir, cur_dir, el_dir, off_ke, cur_ke, el_ke, off_ek, cur_ek, el_ek);

  gat_gather<<<(2 * KN + IN_ + 3) / 4, 256, 0, stream>>>(
      off_dir, el_dir, dsrc, sds, sdd, z_dir, Am,
      off_ke,  el_ke,  kesrc, sks, skd, z_ke, Bmat,
      off_ek,  el_ek,  eksrc, ses, sed, z_ek, out + (size_t)KN * 128);

  gemm128<<<(KN + 63) / 64, 256, 0, stream>>>(Am, Am, KN, rW1, rb1, TA, KN);
  gemm128<<<(KN + 63) / 64, 256, 0, stream>>>(Bmat, Bmat, KN, rW1, rb1, TB, KN);
  score_rows<<<(2 * KN + 3) / 4, 256, 0, stream>>>(TA, TB, rw2, s1, s2);
  combine<<<(KN * 32 + 255) / 256, 256, 0, stream>>>(Am, Bmat, s1, s2, out);
}

// Round 2
// 475.332 us; speedup vs baseline: 1.3418x; 1.3418x over previous
//
#include <hip/hip_runtime.h>
#include <math.h>

#define KN   20000
#define IN_  50000
#define DD   128
#define NN   70000
#define E1N  320000
#define E2N  640000

__device__ __forceinline__ float wred_max(float v) {
#pragma unroll
  for (int o = 32; o > 0; o >>= 1) v = fmaxf(v, __shfl_xor(v, o, 64));
  return v;
}
__device__ __forceinline__ float wred_sum(float v) {
#pragma unroll
  for (int o = 32; o > 0; o >>= 1) v += __shfl_xor(v, o, 64);
  return v;
}

__device__ __forceinline__ unsigned short f2bf(float x) {
  unsigned u = __float_as_uint(x);
  unsigned r = (u + 0x7FFFu + ((u >> 16) & 1u)) >> 16;   // RNE
  return (unsigned short)r;
}
__device__ __forceinline__ unsigned packbf(float a, float b) {
  return (unsigned)f2bf(a) | ((unsigned)f2bf(b) << 16);
}
__device__ __forceinline__ float bf_lo(unsigned u) { return __uint_as_float(u << 16); }
__device__ __forceinline__ float bf_hi(unsigned u) { return __uint_as_float(u & 0xFFFF0000u); }

// z = concat(h1,h2)[row] @ W.  mode 0: write bf16 z (zb, 64 uints/row) and
// per-row dots with avec[:128]/avec[128:] -> ssrc/sdst.
// mode 1: s = sum_j tanh(z[row][j]+bias[j])*w2[j] -> s1 (row<split) / s2.
// Block: 256 thr, 64 rows x 128 cols; thread: 4 rows x 8 cols.
__global__ __launch_bounds__(256, 2) void gemm128(
    const float* __restrict__ h1, const float* __restrict__ h2, int split,
    const float* __restrict__ W, const float* __restrict__ bias, int mode,
    unsigned* __restrict__ zb, const float* __restrict__ avec,
    float* __restrict__ ssrc, float* __restrict__ sdst,
    const float* __restrict__ w2, float* __restrict__ s1, float* __restrict__ s2,
    int rows)
{
  __shared__ float Wl[128 * 128];
  const int tid = threadIdx.x;
  // store W^T swizzled: element (k,c) -> Wl[c*128 + ((k>>2)^((c>>3)&7))*4 + (k&3)]
  for (int idx = tid; idx < 16384; idx += 256) {
    int k = idx >> 7, c = idx & 127;
    Wl[c * 128 + ((((k >> 2) ^ ((c >> 3) & 7)) << 2) | (k & 3))] = W[idx];
  }
  __syncthreads();

  const int tc = tid & 15;
  const int tr = tid >> 4;
  const int r0 = blockIdx.x * 64 + tr * 4;

  const float* hp[4];
  int rowv[4];
#pragma unroll
  for (int i = 0; i < 4; ++i) {
    int r = r0 + i;
    rowv[i] = r;
    int rc = (r < rows) ? r : (rows - 1);
    hp[i] = (rc < split) ? (h1 + (size_t)rc * 128) : (h2 + (size_t)(rc - split) * 128);
  }

  float acc[4][8];
#pragma unroll
  for (int i = 0; i < 4; ++i)
#pragma unroll
    for (int j = 0; j < 8; ++j) acc[i][j] = 0.f;

  const int swz = tc & 7;
  for (int k0 = 0; k0 < 128; k0 += 4) {
    float4 hv[4];
#pragma unroll
    for (int i = 0; i < 4; ++i) hv[i] = *(const float4*)(hp[i] + k0);
    const int kk = (((k0 >> 2) ^ swz) << 2);
    float4 wv[8];
#pragma unroll
    for (int j = 0; j < 8; ++j)
      wv[j] = *(const float4*)&Wl[(8 * tc + j) * 128 + kk];
#pragma unroll
    for (int i = 0; i < 4; ++i)
#pragma unroll
      for (int j = 0; j < 8; ++j)
        acc[i][j] += hv[i].x * wv[j].x + hv[i].y * wv[j].y +
                     hv[i].z * wv[j].z + hv[i].w * wv[j].w;
  }

  if (mode == 0) {
    // bf16 z store: cols 8tc..8tc+7 == uints 4tc..4tc+3 of the row
    float a1[8], a2[8];
    {
      float4 t0 = *(const float4*)(avec + 8 * tc);
      float4 t1 = *(const float4*)(avec + 8 * tc + 4);
      a1[0]=t0.x; a1[1]=t0.y; a1[2]=t0.z; a1[3]=t0.w;
      a1[4]=t1.x; a1[5]=t1.y; a1[6]=t1.z; a1[7]=t1.w;
      float4 t2 = *(const float4*)(avec + 128 + 8 * tc);
      float4 t3 = *(const float4*)(avec + 128 + 8 * tc + 4);
      a2[0]=t2.x; a2[1]=t2.y; a2[2]=t2.z; a2[3]=t2.w;
      a2[4]=t3.x; a2[5]=t3.y; a2[6]=t3.z; a2[7]=t3.w;
    }
#pragma unroll
    for (int i = 0; i < 4; ++i) {
      float d1 = 0.f, d2 = 0.f;
#pragma unroll
      for (int j = 0; j < 8; ++j) { d1 += acc[i][j] * a1[j]; d2 += acc[i][j] * a2[j]; }
#pragma unroll
      for (int o = 1; o < 16; o <<= 1) {
        d1 += __shfl_xor(d1, o, 64);
        d2 += __shfl_xor(d2, o, 64);
      }
      if (rowv[i] < rows) {
        uint4 pk;
        pk.x = packbf(acc[i][0], acc[i][1]);
        pk.y = packbf(acc[i][2], acc[i][3]);
        pk.z = packbf(acc[i][4], acc[i][5]);
        pk.w = packbf(acc[i][6], acc[i][7]);
        *(uint4*)(zb + (size_t)rowv[i] * 64 + 4 * tc) = pk;
        if (tc == 0) { ssrc[rowv[i]] = d1; sdst[rowv[i]] = d2; }
      }
    }
  } else {
    float bv[8], wv2[8];
    {
      float4 t0 = *(const float4*)(bias + 8 * tc);
      float4 t1 = *(const float4*)(bias + 8 * tc + 4);
      bv[0]=t0.x; bv[1]=t0.y; bv[2]=t0.z; bv[3]=t0.w;
      bv[4]=t1.x; bv[5]=t1.y; bv[6]=t1.z; bv[7]=t1.w;
      float4 t2 = *(const float4*)(w2 + 8 * tc);
      float4 t3 = *(const float4*)(w2 + 8 * tc + 4);
      wv2[0]=t2.x; wv2[1]=t2.y; wv2[2]=t2.z; wv2[3]=t2.w;
      wv2[4]=t3.x; wv2[5]=t3.y; wv2[6]=t3.z; wv2[7]=t3.w;
    }
#pragma unroll
    for (int i = 0; i < 4; ++i) {
      float p = 0.f;
#pragma unroll
      for (int j = 0; j < 8; ++j) p += tanhf(acc[i][j] + bv[j]) * wv2[j];
#pragma unroll
      for (int o = 1; o < 16; o <<= 1) p += __shfl_xor(p, o, 64);
      if (tc == 0 && rowv[i] < rows) {
        if (rowv[i] < split) s1[rowv[i]] = p;
        else                 s2[rowv[i] - split] = p;
      }
    }
  }
}

__global__ __launch_bounds__(256) void count_edges(
    const int* __restrict__ ddst, const int* __restrict__ kedst, const int* __restrict__ ekdst,
    int* __restrict__ cnt_dir, int* __restrict__ cnt_ke, int* __restrict__ cnt_ek)
{
  int i = blockIdx.x * 256 + threadIdx.x;
  if (i < E1N) {
    atomicAdd(&cnt_dir[ddst[i]], 1);
  } else if (i < E1N + E2N) {
    int d = kedst[i - E1N];
    if (d >= IN_) atomicAdd(&cnt_ke[d - IN_], 1);
  } else if (i < E1N + 2 * E2N) {
    int d = ekdst[i - E1N - E2N];
    if (d < IN_) atomicAdd(&cnt_ek[d], 1);
  }
}

// 3 independent single-block exclusive scans, shuffle-based (3 barriers/chunk)
__global__ __launch_bounds__(1024) void scan3(
    const int* __restrict__ c0, int* __restrict__ o0, int n0,
    const int* __restrict__ c1, int* __restrict__ o1, int n1,
    const int* __restrict__ c2, int* __restrict__ o2, int n2)
{
  const int* cnt; int* off; int n;
  if (blockIdx.x == 0)      { cnt = c0; off = o0; n = n0; }
  else if (blockIdx.x == 1) { cnt = c1; off = o1; n = n1; }
  else                      { cnt = c2; off = o2; n = n2; }

  __shared__ int wsum[16];
  const int tid = threadIdx.x, lane = tid & 63, wv = tid >> 6;
  int carry = 0;
  for (int base = 0; base < n; base += 4096) {
    int i0 = base + tid * 4;
    int v[4];
#pragma unroll
    for (int j = 0; j < 4; ++j) v[j] = (i0 + j < n) ? cnt[i0 + j] : 0;
    int s = v[0] + v[1] + v[2] + v[3];
    int x = s;
#pragma unroll
    for (int o = 1; o < 64; o <<= 1) {
      int t = __shfl_up(x, o, 64);
      if (lane >= o) x += t;
    }
    if (lane == 63) wsum[wv] = x;
    __syncthreads();
    if (tid < 16) {
      int y = wsum[tid];
#pragma unroll
      for (int o = 1; o < 16; o <<= 1) {
        int t = __shfl_up(y, o, 16);
        if ((tid & 15) >= o) y += t;
      }
      wsum[tid] = y;
    }
    __syncthreads();
    int wbase = wv ? wsum[wv - 1] : 0;
    int total = wsum[15];
    int run = carry + wbase + x - s;
#pragma unroll
    for (int j = 0; j < 4; ++j) {
      if (i0 + j < n) off[i0 + j] = run;
      run += v[j];
    }
    carry += total;
    __syncthreads();
  }
  if (tid == 0) off[n] = carry;
}

// store SRC node id directly (kills one indirection in the gather)
__global__ __launch_bounds__(256) void fill_edges(
    const int* __restrict__ dsrc, const int* __restrict__ ddst,
    const int* __restrict__ kesrc, const int* __restrict__ kedst,
    const int* __restrict__ eksrc, const int* __restrict__ ekdst,
    const int* __restrict__ off_dir, int* __restrict__ cur_dir, int* __restrict__ el_dir,
    const int* __restrict__ off_ke,  int* __restrict__ cur_ke,  int* __restrict__ el_ke,
    const int* __restrict__ off_ek,  int* __restrict__ cur_ek,  int* __restrict__ el_ek)
{
  int i = blockIdx.x * 256 + threadIdx.x;
  if (i < E1N) {
    int d = ddst[i];
    int pos = off_dir[d] + atomicAdd(&cur_dir[d], 1);
    el_dir[pos] = dsrc[i];
  } else if (i < E1N + E2N) {
    int e = i - E1N;
    int d = kedst[e];
    if (d >= IN_) {
      int seg = d - IN_;
      int pos = off_ke[seg] + atomicAdd(&cur_ke[seg], 1);
      el_ke[pos] = kesrc[e];
    }
  } else if (i < E1N + 2 * E2N) {
    int e = i - E1N - E2N;
    int d = ekdst[e];
    if (d < IN_) {
      int pos = off_ek[d] + atomicAdd(&cur_ek[d], 1);
      el_ek[pos] = eksrc[e];
    }
  }
}

// One wave per dst segment. 4 groups x 16 lanes; each group gathers one bf16
// row (16B/lane); manual 2x unroll -> 8 row-loads in flight per wave.
__global__ __launch_bounds__(256) void gat_gather(
    const int* __restrict__ off_dir, const int* __restrict__ el_dir,
    const float* __restrict__ sds, const float* __restrict__ sdd,
    const unsigned* __restrict__ zb_dir, float* __restrict__ A,
    const int* __restrict__ off_ke, const int* __restrict__ el_ke,
    const float* __restrict__ sks, const float* __restrict__ skd,
    const unsigned* __restrict__ zb_ke, float* __restrict__ Bm,
    const int* __restrict__ off_ek, const int* __restrict__ el_ek,
    const float* __restrict__ ses, const float* __restrict__ sed,
    const unsigned* __restrict__ zb_ek, float* __restrict__ Cout)
{
  int w = (blockIdx.x * 256 + threadIdx.x) >> 6;
  int lane = threadIdx.x & 63;
  int gid = lane >> 4, gl = lane & 15;
  const int *off, *el;
  const float *sS, *sD;
  const unsigned* zb;
  float* out;
  int seg, node;
  if (w < KN)                { seg = w;          node = seg;       off = off_dir; el = el_dir; sS = sds; sD = sdd; zb = zb_dir; out = A; }
  else if (w < 2 * KN)       { seg = w - KN;     node = seg + IN_; off = off_ke;  el = el_ke;  sS = sks; sD = skd; zb = zb_ke;  out = Bm; }
  else if (w < 2 * KN + IN_) { seg = w - 2 * KN; node = seg;       off = off_ek;  el = el_ek;  sS = ses; sD = sed; zb = zb_ek;  out = Cout; }
  else return;

  int b = off[seg], e = off[seg + 1];
  float av[8];
#pragma unroll
  for (int k = 0; k < 8; ++k) av[k] = 0.f;

  if (e > b) {
    float sd = sD[node];
    float m = -INFINITY;
    for (int i = b + lane; i < e; i += 64) {
      float x = sS[el[i]] + sd;
      x = (x > 0.f) ? x : 0.01f * x;
      m = fmaxf(m, x);
    }
    m = wred_max(m);
    float den = 0.f;
    for (int i = b + lane; i < e; i += 64) {
      float x = sS[el[i]] + sd;
      x = (x > 0.f) ? x : 0.01f * x;
      den += __expf(x - m);
    }
    den = wred_sum(den);
    float inv = 1.f / den;

    int i = b + gid;
    for (; i + 4 < e; i += 8) {
      int sa = el[i], sb = el[i + 4];
      float xa = sS[sa] + sd; xa = (xa > 0.f) ? xa : 0.01f * xa;
      float xb = sS[sb] + sd; xb = (xb > 0.f) ? xb : 0.01f * xb;
      float ala = __expf(xa - m) * inv;
      float alb = __expf(xb - m) * inv;
      uint4 za = *(const uint4*)(zb + (size_t)sa * 64 + gl * 4);
      uint4 zc = *(const uint4*)(zb + (size_t)sb * 64 + gl * 4);
      av[0] += ala * bf_lo(za.x); av[1] += ala * bf_hi(za.x);
      av[2] += ala * bf_lo(za.y); av[3] += ala * bf_hi(za.y);
      av[4] += ala * bf_lo(za.z); av[5] += ala * bf_hi(za.z);
      av[6] += ala * bf_lo(za.w); av[7] += ala * bf_hi(za.w);
      av[0] += alb * bf_lo(zc.x); av[1] += alb * bf_hi(zc.x);
      av[2] += alb * bf_lo(zc.y); av[3] += alb * bf_hi(zc.y);
      av[4] += alb * bf_lo(zc.z); av[5] += alb * bf_hi(zc.z);
      av[6] += alb * bf_lo(zc.w); av[7] += alb * bf_hi(zc.w);
    }
    if (i < e) {
      int sa = el[i];
      float xa = sS[sa] + sd; xa = (xa > 0.f) ? xa : 0.01f * xa;
      float ala = __expf(xa - m) * inv;
      uint4 za = *(const uint4*)(zb + (size_t)sa * 64 + gl * 4);
      av[0] += ala * bf_lo(za.x); av[1] += ala * bf_hi(za.x);
      av[2] += ala * bf_lo(za.y); av[3] += ala * bf_hi(za.y);
      av[4] += ala * bf_lo(za.z); av[5] += ala * bf_hi(za.z);
      av[6] += ala * bf_lo(za.w); av[7] += ala * bf_hi(za.w);
    }
#pragma unroll
    for (int k = 0; k < 8; ++k) {
      av[k] += __shfl_xor(av[k], 16, 64);
      av[k] += __shfl_xor(av[k], 32, 64);
    }
  }

  if (gid == 0) {
    float* op = out + (size_t)seg * 128 + gl * 8;
    *(float4*)op       = make_float4(av[0], av[1], av[2], av[3]);
    *(float4*)(op + 4) = make_float4(av[4], av[5], av[6], av[7]);
  }
}

__global__ __launch_bounds__(256) void combine(
    const float* __restrict__ A, const float* __restrict__ Bm,
    const float* __restrict__ s1, const float* __restrict__ s2,
    float* __restrict__ out)
{
  int i = blockIdx.x * 256 + threadIdx.x;   // float4 index
  if (i >= KN * 32) return;
  int row = i >> 5;
  float a = s1[row], b = s2[row];
  float mm = fmaxf(a, b);
  float e1 = __expf(a - mm), e2 = __expf(b - mm);
  float den = e1 + e2;
  float al = e1 / den, be = e2 / den;
  float4 av = ((const float4*)A)[i];
  float4 bv = ((const float4*)Bm)[i];
  ((float4*)out)[i] = make_float4(al * av.x + be * bv.x, al * av.y + be * bv.y,
                                  al * av.z + be * bv.z, al * av.w + be * bv.w);
}

extern "C" void kernel_launch(void* const* d_in, const int* in_sizes, int n_in,
                              void* d_out, int out_size, void* d_ws, size_t ws_size,
                              hipStream_t stream) {
  const float* kn    = (const float*)d_in[0];
  const float* ex    = (const float*)d_in[1];
  const float* W_dir = (const float*)d_in[2];
  const float* a_dir = (const float*)d_in[3];
  const float* W_ke  = (const float*)d_in[4];
  const float* a_ke  = (const float*)d_in[5];
  const float* W_ek  = (const float*)d_in[6];
  const float* a_ek  = (const float*)d_in[7];
  const float* rW1   = (const float*)d_in[8];
  const float* rb1   = (const float*)d_in[9];
  const float* rw2   = (const float*)d_in[10];
  const int* dsrc    = (const int*)d_in[11];
  const int* ddst    = (const int*)d_in[12];
  const int* kesrc   = (const int*)d_in[13];
  const int* kedst   = (const int*)d_in[14];
  const int* eksrc   = (const int*)d_in[15];
  const int* ekdst   = (const int*)d_in[16];
  float* out = (float*)d_out;

  char* p = (char*)d_ws;
  auto alloc = [&](size_t bytes) {
    char* r = p;
    p += (bytes + 255) & ~(size_t)255;
    return r;
  };
  unsigned* zb_dir = (unsigned*)alloc((size_t)KN * 64 * 4);
  unsigned* zb_ke  = (unsigned*)alloc((size_t)NN * 64 * 4);
  unsigned* zb_ek  = (unsigned*)alloc((size_t)NN * 64 * 4);
  float* Am    = (float*)alloc((size_t)KN * 128 * 4);
  float* Bmat  = (float*)alloc((size_t)KN * 128 * 4);
  float* sds = (float*)alloc(KN * 4);
  float* sdd = (float*)alloc(KN * 4);
  float* sks = (float*)alloc(NN * 4);
  float* skd = (float*)alloc(NN * 4);
  float* ses = (float*)alloc(NN * 4);
  float* sed = (float*)alloc(NN * 4);
  float* s1  = (float*)alloc(KN * 4);
  float* s2  = (float*)alloc(KN * 4);
  int* cntblk  = (int*)alloc((size_t)(4 * KN + 2 * IN_) * 4);
  int* cnt_dir = cntblk;
  int* cur_dir = cntblk + KN;
  int* cnt_ke  = cntblk + 2 * KN;
  int* cur_ke  = cntblk + 3 * KN;
  int* cnt_ek  = cntblk + 4 * KN;
  int* cur_ek  = cntblk + 4 * KN + IN_;
  int* off_dir = (int*)alloc((KN + 1) * 4);
  int* off_ke  = (int*)alloc((KN + 1) * 4);
  int* off_ek  = (int*)alloc((IN_ + 1) * 4);
  int* el_dir  = (int*)alloc((size_t)E1N * 4);
  int* el_ke   = (int*)alloc((size_t)E2N * 4);
  int* el_ek   = (int*)alloc((size_t)E2N * 4);

  hipMemsetAsync(cntblk, 0, (size_t)(4 * KN + 2 * IN_) * 4, stream);

  gemm128<<<(KN + 63) / 64, 256, 0, stream>>>(kn, kn, KN, W_dir, nullptr, 0,
      zb_dir, a_dir, sds, sdd, nullptr, nullptr, nullptr, KN);
  gemm128<<<(NN + 63) / 64, 256, 0, stream>>>(ex, kn, IN_, W_ke, nullptr, 0,
      zb_ke, a_ke, sks, skd, nullptr, nullptr, nullptr, NN);
  gemm128<<<(NN + 63) / 64, 256, 0, stream>>>(ex, kn, IN_, W_ek, nullptr, 0,
      zb_ek, a_ek, ses, sed, nullptr, nullptr, nullptr, NN);

  count_edges<<<(E1N + 2 * E2N + 255) / 256, 256, 0, stream>>>(ddst, kedst, ekdst,
                                                               cnt_dir, cnt_ke, cnt_ek);
  scan3<<<3, 1024, 0, stream>>>(cnt_dir, off_dir, KN, cnt_ke, off_ke, KN, cnt_ek, off_ek, IN_);
  fill_edges<<<(E1N + 2 * E2N + 255) / 256, 256, 0, stream>>>(
      dsrc, ddst, kesrc, kedst, eksrc, ekdst,
      off_dir, cur_dir, el_dir, off_ke, cur_ke, el_ke, off_ek, cur_ek, el_ek);

  gat_gather<<<(2 * KN + IN_ + 3) / 4, 256, 0, stream>>>(
      off_dir, el_dir, sds, sdd, zb_dir, Am,
      off_ke,  el_ke,  sks, skd, zb_ke,  Bmat,
      off_ek,  el_ek,  ses, sed, zb_ek,  out + (size_t)KN * 128);

  gemm128<<<(2 * KN + 63) / 64, 256, 0, stream>>>(Am, Bmat, KN, rW1, rb1, 1,
      nullptr, nullptr, nullptr, nullptr, rw2, s1, s2, 2 * KN);
  combine<<<(KN * 32 + 255) / 256, 256, 0, stream>>>(Am, Bmat, s1, s2, out);
}

// Round 3
// 380.847 us; speedup vs baseline: 1.6747x; 1.2481x over previous
//
#include <hip/hip_runtime.h>
#include <math.h>

#define KN   20000
#define IN_  50000
#define DD   128
#define NN   70000
#define E1N  320000
#define E2N  640000

typedef short bf16x8 __attribute__((ext_vector_type(8)));
typedef float floatx4 __attribute__((ext_vector_type(4)));

__device__ __forceinline__ float wred_max(float v) {
#pragma unroll
  for (int o = 32; o > 0; o >>= 1) v = fmaxf(v, __shfl_xor(v, o, 64));
  return v;
}
__device__ __forceinline__ float wred_sum(float v) {
#pragma unroll
  for (int o = 32; o > 0; o >>= 1) v += __shfl_xor(v, o, 64);
  return v;
}

__device__ __forceinline__ unsigned f2bf(float x) {
  unsigned u = __float_as_uint(x);
  return (u + 0x7FFFu + ((u >> 16) & 1u)) >> 16;   // RNE
}
__device__ __forceinline__ unsigned packbf(float a, float b) {
  return f2bf(a) | (f2bf(b) << 16);
}
__device__ __forceinline__ float bf_lo(unsigned u) { return __uint_as_float(u << 16); }
__device__ __forceinline__ float bf_hi(unsigned u) { return __uint_as_float(u & 0xFFFF0000u); }

// MFMA GEMM: z = concat(h1,h2)[row] @ W, computed as z^T tiles via
// D = (W^T-frag as A-op) x (emb-frag as B-op), 16x16x32 bf16, 3-term hi/lo
// split for ~fp32 accuracy.
// mode 0: write bf16 z rows (zb, 64 uints/row) + row dots with avec -> ssrc/sdst
// mode 1: s[row] = sum_j tanh(z[row][j]+bias[j])*w2[j] -> s1 (row<split) / s2
// Block 256 = 4 waves; block covers 64 rows (16/wave), all 128 cols.
__global__ __launch_bounds__(256, 2) void gemm_mfma(
    const float* __restrict__ h1, const float* __restrict__ h2, int split,
    const float* __restrict__ W, const float* __restrict__ bias, int mode,
    unsigned* __restrict__ zb, const float* __restrict__ avec,
    float* __restrict__ ssrc, float* __restrict__ sdst,
    const float* __restrict__ w2, float* __restrict__ s1, float* __restrict__ s2,
    int rows)
{
  __shared__ short Wh[16384];   // W hi-bf16, fragment order: ((t*4+chunk)*64+lane)*8
  __shared__ short Wlo[16384];  // W lo-bf16 residual
  const int tid = threadIdx.x;
  const int lane = tid & 63;
  const int wv = tid >> 6;
  const int q = lane >> 4;      // quad
  const int m = lane & 15;

  // Stage W as bf16 hi/lo fragments. Per iteration: wave covers (t=it, chunk=wv),
  // lane l holds W[chunk*32 + (l>>4)*8 + j][it*16 + (l&15)], j=0..7.
  for (int it = 0; it < 8; ++it) {
    int fi = it * 256 + tid;
    int chunk = (fi >> 6) & 3;
    int l = fi & 63;
    int col = it * 16 + (l & 15);
    int kbase = chunk * 32 + (l >> 4) * 8;
    bf16x8 hv, lv;
#pragma unroll
    for (int j = 0; j < 8; ++j) {
      float v = W[(kbase + j) * 128 + col];
      unsigned hb = f2bf(v);
      hv[j] = (short)hb;
      lv[j] = (short)f2bf(v - __uint_as_float(hb << 16));
    }
    *(bf16x8*)&Wh[fi * 8] = hv;
    *(bf16x8*)&Wlo[fi * 8] = lv;
  }
  __syncthreads();

  const int r0 = blockIdx.x * 64 + wv * 16;
  const int r = r0 + m;                 // this lane's z-row (all quads share it)
  const int rc = (r < rows) ? r : (rows - 1);
  const float* hp = (rc < split) ? (h1 + (size_t)rc * 128)
                                 : (h2 + (size_t)(rc - split) * 128);

  floatx4 acc[8];
#pragma unroll
  for (int t = 0; t < 8; ++t) { acc[t][0] = 0.f; acc[t][1] = 0.f; acc[t][2] = 0.f; acc[t][3] = 0.f; }

#pragma unroll
  for (int chunk = 0; chunk < 4; ++chunk) {
    // B-operand (emb): lane holds h[r][chunk*32 + q*8 + j], j=0..7
    float4 v0 = *(const float4*)(hp + chunk * 32 + q * 8);
    float4 v1 = *(const float4*)(hp + chunk * 32 + q * 8 + 4);
    float vs[8] = {v0.x, v0.y, v0.z, v0.w, v1.x, v1.y, v1.z, v1.w};
    bf16x8 ahi, alo;
#pragma unroll
    for (int j = 0; j < 8; ++j) {
      unsigned hb = f2bf(vs[j]);
      ahi[j] = (short)hb;
      alo[j] = (short)f2bf(vs[j] - __uint_as_float(hb << 16));
    }
#pragma unroll
    for (int t = 0; t < 8; ++t) {
      bf16x8 bh = *(const bf16x8*)&Wh[((t * 4 + chunk) * 64 + lane) * 8];
      bf16x8 bl = *(const bf16x8*)&Wlo[((t * 4 + chunk) * 64 + lane) * 8];
      acc[t] = __builtin_amdgcn_mfma_f32_16x16x32_bf16(bh, ahi, acc[t], 0, 0, 0);
      acc[t] = __builtin_amdgcn_mfma_f32_16x16x32_bf16(bl, ahi, acc[t], 0, 0, 0);
      acc[t] = __builtin_amdgcn_mfma_f32_16x16x32_bf16(bh, alo, acc[t], 0, 0, 0);
    }
  }
  // D layout: n(col)=lane&15 = z-row (fixed per lane); m(row)=q*4+reg = z-col
  // within tile t -> lane's z-cols are t*16 + q*4 + {0..3}: 4 consecutive.

  if (mode == 0) {
    if (r < rows) {
      unsigned* zrow = zb + (size_t)r * 64;
#pragma unroll
      for (int t = 0; t < 8; ++t) {
        uint2 pk;
        pk.x = packbf(acc[t][0], acc[t][1]);
        pk.y = packbf(acc[t][2], acc[t][3]);
        *(uint2*)(zrow + t * 8 + q * 2) = pk;
      }
    }
    float d1 = 0.f, d2 = 0.f;
#pragma unroll
    for (int t = 0; t < 8; ++t) {
      float4 wa = *(const float4*)(avec + t * 16 + q * 4);
      float4 wb = *(const float4*)(avec + 128 + t * 16 + q * 4);
      d1 += acc[t][0] * wa.x + acc[t][1] * wa.y + acc[t][2] * wa.z + acc[t][3] * wa.w;
      d2 += acc[t][0] * wb.x + acc[t][1] * wb.y + acc[t][2] * wb.z + acc[t][3] * wb.w;
    }
    d1 += __shfl_xor(d1, 16, 64); d1 += __shfl_xor(d1, 32, 64);
    d2 += __shfl_xor(d2, 16, 64); d2 += __shfl_xor(d2, 32, 64);
    if (q == 0 && r < rows) { ssrc[r] = d1; sdst[r] = d2; }
  } else {
    float p = 0.f;
#pragma unroll
    for (int t = 0; t < 8; ++t) {
      float4 bb = *(const float4*)(bias + t * 16 + q * 4);
      float4 ww = *(const float4*)(w2 + t * 16 + q * 4);
      p += tanhf(acc[t][0] + bb.x) * ww.x + tanhf(acc[t][1] + bb.y) * ww.y +
           tanhf(acc[t][2] + bb.z) * ww.z + tanhf(acc[t][3] + bb.w) * ww.w;
    }
    p += __shfl_xor(p, 16, 64); p += __shfl_xor(p, 32, 64);
    if (q == 0 && r < rows) {
      if (r < split) s1[r] = p;
      else           s2[r - split] = p;
    }
  }
}

__global__ __launch_bounds__(256) void count_edges(
    const int* __restrict__ ddst, const int* __restrict__ kedst, const int* __restrict__ ekdst,
    int* __restrict__ cnt_dir, int* __restrict__ cnt_ke, int* __restrict__ cnt_ek)
{
  int i = blockIdx.x * 256 + threadIdx.x;
  if (i < E1N) {
    atomicAdd(&cnt_dir[ddst[i]], 1);
  } else if (i < E1N + E2N) {
    int d = kedst[i - E1N];
    if (d >= IN_) atomicAdd(&cnt_ke[d - IN_], 1);
  } else if (i < E1N + 2 * E2N) {
    int d = ekdst[i - E1N - E2N];
    if (d < IN_) atomicAdd(&cnt_ek[d], 1);
  }
}

// 3 independent single-block exclusive scans, shuffle-based
__global__ __launch_bounds__(1024) void scan3(
    const int* __restrict__ c0, int* __restrict__ o0, int n0,
    const int* __restrict__ c1, int* __restrict__ o1, int n1,
    const int* __restrict__ c2, int* __restrict__ o2, int n2)
{
  const int* cnt; int* off; int n;
  if (blockIdx.x == 0)      { cnt = c0; off = o0; n = n0; }
  else if (blockIdx.x == 1) { cnt = c1; off = o1; n = n1; }
  else                      { cnt = c2; off = o2; n = n2; }

  __shared__ int wsum[16];
  const int tid = threadIdx.x, lane = tid & 63, wv = tid >> 6;
  int carry = 0;
  for (int base = 0; base < n; base += 4096) {
    int i0 = base + tid * 4;
    int v[4];
#pragma unroll
    for (int j = 0; j < 4; ++j) v[j] = (i0 + j < n) ? cnt[i0 + j] : 0;
    int s = v[0] + v[1] + v[2] + v[3];
    int x = s;
#pragma unroll
    for (int o = 1; o < 64; o <<= 1) {
      int t = __shfl_up(x, o, 64);
      if (lane >= o) x += t;
    }
    if (lane == 63) wsum[wv] = x;
    __syncthreads();
    if (tid < 16) {
      int y = wsum[tid];
#pragma unroll
      for (int o = 1; o < 16; o <<= 1) {
        int t = __shfl_up(y, o, 16);
        if ((tid & 15) >= o) y += t;
      }
      wsum[tid] = y;
    }
    __syncthreads();
    int wbase = wv ? wsum[wv - 1] : 0;
    int total = wsum[15];
    int run = carry + wbase + x - s;
#pragma unroll
    for (int j = 0; j < 4; ++j) {
      if (i0 + j < n) off[i0 + j] = run;
      run += v[j];
    }
    carry += total;
    __syncthreads();
  }
  if (tid == 0) off[n] = carry;
}

// store SRC node id directly
__global__ __launch_bounds__(256) void fill_edges(
    const int* __restrict__ dsrc, const int* __restrict__ ddst,
    const int* __restrict__ kesrc, const int* __restrict__ kedst,
    const int* __restrict__ eksrc, const int* __restrict__ ekdst,
    const int* __restrict__ off_dir, int* __restrict__ cur_dir, int* __restrict__ el_dir,
    const int* __restrict__ off_ke,  int* __restrict__ cur_ke,  int* __restrict__ el_ke,
    const int* __restrict__ off_ek,  int* __restrict__ cur_ek,  int* __restrict__ el_ek)
{
  int i = blockIdx.x * 256 + threadIdx.x;
  if (i < E1N) {
    int d = ddst[i];
    int pos = off_dir[d] + atomicAdd(&cur_dir[d], 1);
    el_dir[pos] = dsrc[i];
  } else if (i < E1N + E2N) {
    int e = i - E1N;
    int d = kedst[e];
    if (d >= IN_) {
      int seg = d - IN_;
      int pos = off_ke[seg] + atomicAdd(&cur_ke[seg], 1);
      el_ke[pos] = kesrc[e];
    }
  } else if (i < E1N + 2 * E2N) {
    int e = i - E1N - E2N;
    int d = ekdst[e];
    if (d < IN_) {
      int pos = off_ek[d] + atomicAdd(&cur_ek[d], 1);
      el_ek[pos] = eksrc[e];
    }
  }
}

// One wave per dst segment. 4 groups x 16 lanes; each group gathers one bf16
// row (16B/lane); 2x unroll -> 8 row-loads in flight per wave.
__global__ __launch_bounds__(256) void gat_gather(
    const int* __restrict__ off_dir, const int* __restrict__ el_dir,
    const float* __restrict__ sds, const float* __restrict__ sdd,
    const unsigned* __restrict__ zb_dir, float* __restrict__ A,
    const int* __restrict__ off_ke, const int* __restrict__ el_ke,
    const float* __restrict__ sks, const float* __restrict__ skd,
    const unsigned* __restrict__ zb_ke, float* __restrict__ Bm,
    const int* __restrict__ off_ek, const int* __restrict__ el_ek,
    const float* __restrict__ ses, const float* __restrict__ sed,
    const unsigned* __restrict__ zb_ek, float* __restrict__ Cout)
{
  int w = (blockIdx.x * 256 + threadIdx.x) >> 6;
  int lane = threadIdx.x & 63;
  int gid = lane >> 4, gl = lane & 15;
  const int *off, *el;
  const float *sS, *sD;
  const unsigned* zb;
  float* out;
  int seg, node;
  if (w < KN)                { seg = w;          node = seg;       off = off_dir; el = el_dir; sS = sds; sD = sdd; zb = zb_dir; out = A; }
  else if (w < 2 * KN)       { seg = w - KN;     node = seg + IN_; off = off_ke;  el = el_ke;  sS = sks; sD = skd; zb = zb_ke;  out = Bm; }
  else if (w < 2 * KN + IN_) { seg = w - 2 * KN; node = seg;       off = off_ek;  el = el_ek;  sS = ses; sD = sed; zb = zb_ek;  out = Cout; }
  else return;

  int b = off[seg], e = off[seg + 1];
  float av[8];
#pragma unroll
  for (int k = 0; k < 8; ++k) av[k] = 0.f;

  if (e > b) {
    float sd = sD[node];
    float m = -INFINITY;
    for (int i = b + lane; i < e; i += 64) {
      float x = sS[el[i]] + sd;
      x = (x > 0.f) ? x : 0.01f * x;
      m = fmaxf(m, x);
    }
    m = wred_max(m);
    float den = 0.f;
    for (int i = b + lane; i < e; i += 64) {
      float x = sS[el[i]] + sd;
      x = (x > 0.f) ? x : 0.01f * x;
      den += __expf(x - m);
    }
    den = wred_sum(den);
    float inv = 1.f / den;

    int i = b + gid;
    for (; i + 4 < e; i += 8) {
      int sa = el[i], sb = el[i + 4];
      float xa = sS[sa] + sd; xa = (xa > 0.f) ? xa : 0.01f * xa;
      float xb = sS[sb] + sd; xb = (xb > 0.f) ? xb : 0.01f * xb;
      float ala = __expf(xa - m) * inv;
      float alb = __expf(xb - m) * inv;
      uint4 za = *(const uint4*)(zb + (size_t)sa * 64 + gl * 4);
      uint4 zc = *(const uint4*)(zb + (size_t)sb * 64 + gl * 4);
      av[0] += ala * bf_lo(za.x); av[1] += ala * bf_hi(za.x);
      av[2] += ala * bf_lo(za.y); av[3] += ala * bf_hi(za.y);
      av[4] += ala * bf_lo(za.z); av[5] += ala * bf_hi(za.z);
      av[6] += ala * bf_lo(za.w); av[7] += ala * bf_hi(za.w);
      av[0] += alb * bf_lo(zc.x); av[1] += alb * bf_hi(zc.x);
      av[2] += alb * bf_lo(zc.y); av[3] += alb * bf_hi(zc.y);
      av[4] += alb * bf_lo(zc.z); av[5] += alb * bf_hi(zc.z);
      av[6] += alb * bf_lo(zc.w); av[7] += alb * bf_hi(zc.w);
    }
    if (i < e) {
      int sa = el[i];
      float xa = sS[sa] + sd; xa = (xa > 0.f) ? xa : 0.01f * xa;
      float ala = __expf(xa - m) * inv;
      uint4 za = *(const uint4*)(zb + (size_t)sa * 64 + gl * 4);
      av[0] += ala * bf_lo(za.x); av[1] += ala * bf_hi(za.x);
      av[2] += ala * bf_lo(za.y); av[3] += ala * bf_hi(za.y);
      av[4] += ala * bf_lo(za.z); av[5] += ala * bf_hi(za.z);
      av[6] += ala * bf_lo(za.w); av[7] += ala * bf_hi(za.w);
    }
#pragma unroll
    for (int k = 0; k < 8; ++k) {
      av[k] += __shfl_xor(av[k], 16, 64);
      av[k] += __shfl_xor(av[k], 32, 64);
    }
  }

  if (gid == 0) {
    float* op = out + (size_t)seg * 128 + gl * 8;
    *(float4*)op       = make_float4(av[0], av[1], av[2], av[3]);
    *(float4*)(op + 4) = make_float4(av[4], av[5], av[6], av[7]);
  }
}

__global__ __launch_bounds__(256) void combine(
    const float* __restrict__ A, const float* __restrict__ Bm,
    const float* __restrict__ s1, const float* __restrict__ s2,
    float* __restrict__ out)
{
  int i = blockIdx.x * 256 + threadIdx.x;   // float4 index
  if (i >= KN * 32) return;
  int row = i >> 5;
  float a = s1[row], b = s2[row];
  float mm = fmaxf(a, b);
  float e1 = __expf(a - mm), e2 = __expf(b - mm);
  float den = e1 + e2;
  float al = e1 / den, be = e2 / den;
  float4 av = ((const float4*)A)[i];
  float4 bv = ((const float4*)Bm)[i];
  ((float4*)out)[i] = make_float4(al * av.x + be * bv.x, al * av.y + be * bv.y,
                                  al * av.z + be * bv.z, al * av.w + be * bv.w);
}

extern "C" void kernel_launch(void* const* d_in, const int* in_sizes, int n_in,
                              void* d_out, int out_size, void* d_ws, size_t ws_size,
                              hipStream_t stream) {
  const float* kn    = (const float*)d_in[0];
  const float* ex    = (const float*)d_in[1];
  const float* W_dir = (const float*)d_in[2];
  const float* a_dir = (const float*)d_in[3];
  const float* W_ke  = (const float*)d_in[4];
  const float* a_ke  = (const float*)d_in[5];
  const float* W_ek  = (const float*)d_in[6];
  const float* a_ek  = (const float*)d_in[7];
  const float* rW1   = (const float*)d_in[8];
  const float* rb1   = (const float*)d_in[9];
  const float* rw2   = (const float*)d_in[10];
  const int* dsrc    = (const int*)d_in[11];
  const int* ddst    = (const int*)d_in[12];
  const int* kesrc   = (const int*)d_in[13];
  const int* kedst   = (const int*)d_in[14];
  const int* eksrc   = (const int*)d_in[15];
  const int* ekdst   = (const int*)d_in[16];
  float* out = (float*)d_out;

  char* p = (char*)d_ws;
  auto alloc = [&](size_t bytes) {
    char* r = p;
    p += (bytes + 255) & ~(size_t)255;
    return r;
  };
  unsigned* zb_dir = (unsigned*)alloc((size_t)KN * 64 * 4);
  unsigned* zb_ke  = (unsigned*)alloc((size_t)NN * 64 * 4);
  unsigned* zb_ek  = (unsigned*)alloc((size_t)NN * 64 * 4);
  float* Am    = (float*)alloc((size_t)KN * 128 * 4);
  float* Bmat  = (float*)alloc((size_t)KN * 128 * 4);
  float* sds = (float*)alloc(KN * 4);
  float* sdd = (float*)alloc(KN * 4);
  float* sks = (float*)alloc(NN * 4);
  float* skd = (float*)alloc(NN * 4);
  float* ses = (float*)alloc(NN * 4);
  float* sed = (float*)alloc(NN * 4);
  float* s1  = (float*)alloc(KN * 4);
  float* s2  = (float*)alloc(KN * 4);
  int* cntblk  = (int*)alloc((size_t)(4 * KN + 2 * IN_) * 4);
  int* cnt_dir = cntblk;
  int* cur_dir = cntblk + KN;
  int* cnt_ke  = cntblk + 2 * KN;
  int* cur_ke  = cntblk + 3 * KN;
  int* cnt_ek  = cntblk + 4 * KN;
  int* cur_ek  = cntblk + 4 * KN + IN_;
  int* off_dir = (int*)alloc((KN + 1) * 4);
  int* off_ke  = (int*)alloc((KN + 1) * 4);
  int* off_ek  = (int*)alloc((IN_ + 1) * 4);
  int* el_dir  = (int*)alloc((size_t)E1N * 4);
  int* el_ke   = (int*)alloc((size_t)E2N * 4);
  int* el_ek   = (int*)alloc((size_t)E2N * 4);

  hipMemsetAsync(cntblk, 0, (size_t)(4 * KN + 2 * IN_) * 4, stream);

  gemm_mfma<<<(KN + 63) / 64, 256, 0, stream>>>(kn, kn, KN, W_dir, nullptr, 0,
      zb_dir, a_dir, sds, sdd, nullptr, nullptr, nullptr, KN);
  gemm_mfma<<<(NN + 63) / 64, 256, 0, stream>>>(ex, kn, IN_, W_ke, nullptr, 0,
      zb_ke, a_ke, sks, skd, nullptr, nullptr, nullptr, NN);
  gemm_mfma<<<(NN + 63) / 64, 256, 0, stream>>>(ex, kn, IN_, W_ek, nullptr, 0,
      zb_ek, a_ek, ses, sed, nullptr, nullptr, nullptr, NN);

  count_edges<<<(E1N + 2 * E2N + 255) / 256, 256, 0, stream>>>(ddst, kedst, ekdst,
                                                               cnt_dir, cnt_ke, cnt_ek);
  scan3<<<3, 1024, 0, stream>>>(cnt_dir, off_dir, KN, cnt_ke, off_ke, KN, cnt_ek, off_ek, IN_);
  fill_edges<<<(E1N + 2 * E2N + 255) / 256, 256, 0, stream>>>(
      dsrc, ddst, kesrc, kedst, eksrc, ekdst,
      off_dir, cur_dir, el_dir, off_ke, cur_ke, el_ke, off_ek, cur_ek, el_ek);

  gat_gather<<<(2 * KN + IN_ + 3) / 4, 256, 0, stream>>>(
      off_dir, el_dir, sds, sdd, zb_dir, Am,
      off_ke,  el_ke,  sks, skd, zb_ke,  Bmat,
      off_ek,  el_ek,  ses, sed, zb_ek,  out + (size_t)KN * 128);

  gemm_mfma<<<(2 * KN + 63) / 64, 256, 0, stream>>>(Am, Bmat, KN, rW1, rb1, 1,
      nullptr, nullptr, nullptr, nullptr, rw2, s1, s2, 2 * KN);
  combine<<<(KN * 32 + 255) / 256, 256, 0, stream>>>(Am, Bmat, s1, s2, out);
}

// Round 4
// 334.494 us; speedup vs baseline: 1.9068x; 1.1386x over previous
//
#include <hip/hip_runtime.h>
#include <math.h>

#define KN   20000
#define IN_  50000
#define DD   128
#define NN   70000
#define E1N  320000
#define E2N  640000

// fused gemm grid layout
#define NB0  313                 // ceil(20000/64)
#define NB1  1094                // ceil(70000/64)
#define NB2  1094
#define CB0  (NB0 + NB1 + NB2)   // 2501: first count block
#define NCNT 6250                // 1.6M edges / 256

typedef short bf16x8 __attribute__((ext_vector_type(8)));
typedef float floatx4 __attribute__((ext_vector_type(4)));

__device__ __forceinline__ unsigned f2bf(float x) {
  unsigned u = __float_as_uint(x);
  return (u + 0x7FFFu + ((u >> 16) & 1u)) >> 16;   // RNE
}
__device__ __forceinline__ unsigned packbf(float a, float b) {
  return f2bf(a) | (f2bf(b) << 16);
}
__device__ __forceinline__ float bf_lo(unsigned u) { return __uint_as_float(u << 16); }
__device__ __forceinline__ float bf_hi(unsigned u) { return __uint_as_float(u & 0xFFFF0000u); }

// Pre-convert 4 weight matrices into MFMA-fragment-ordered bf16 hi/lo arrays.
// Layout per W (32768 shorts): [0,16384) hi frags, [16384,32768) lo frags;
// fragment fi = (t*4+chunk)*64+lane holds W[chunk*32+(lane>>4)*8+j][t*16+(lane&15)].
__global__ __launch_bounds__(256) void wconv(
    const float* __restrict__ W0, const float* __restrict__ W1,
    const float* __restrict__ W2, const float* __restrict__ W3,
    short* __restrict__ wfr)
{
  int b = blockIdx.x;
  int wsel = b >> 3;
  const float* W = (wsel == 0) ? W0 : (wsel == 1) ? W1 : (wsel == 2) ? W2 : W3;
  int fi = (b & 7) * 256 + threadIdx.x;      // 0..2047
  int l = fi & 63, chunk = (fi >> 6) & 3, t = fi >> 8;
  int col = t * 16 + (l & 15);
  int kbase = chunk * 32 + (l >> 4) * 8;
  bf16x8 hv, lv;
#pragma unroll
  for (int j = 0; j < 8; ++j) {
    float v = W[(kbase + j) * 128 + col];
    unsigned hb = f2bf(v);
    hv[j] = (short)hb;
    lv[j] = (short)f2bf(v - __uint_as_float(hb << 16));
  }
  short* dst = wfr + wsel * 32768;
  *(bf16x8*)&dst[fi * 8] = hv;
  *(bf16x8*)&dst[16384 + fi * 8] = lv;
}

// Fused: 3x MFMA gemms (z = emb @ W, 3-term bf16 split) + count_edges.
// gemm epilogue: bf16 z rows + row dots with avec -> ssrc/sdst.
__global__ __launch_bounds__(256, 2) void fused_gemm_count(
    const float* __restrict__ kn, const float* __restrict__ ex,
    const short* __restrict__ wfr,
    const float* __restrict__ a_dir, const float* __restrict__ a_ke, const float* __restrict__ a_ek,
    unsigned* __restrict__ zb_dir, unsigned* __restrict__ zb_ke, unsigned* __restrict__ zb_ek,
    float* __restrict__ sds, float* __restrict__ sdd,
    float* __restrict__ sks, float* __restrict__ skd,
    float* __restrict__ ses, float* __restrict__ sed,
    const int* __restrict__ ddst, const int* __restrict__ kedst, const int* __restrict__ ekdst,
    int* __restrict__ cnt_dir, int* __restrict__ cnt_ke, int* __restrict__ cnt_ek)
{
  const int bid = blockIdx.x;
  const int tid = threadIdx.x;

  if (bid >= CB0) {
    // ---- count_edges path ----
    int i = (bid - CB0) * 256 + tid;
    if (i < E1N) {
      atomicAdd(&cnt_dir[ddst[i]], 1);
    } else if (i < E1N + E2N) {
      int d = kedst[i - E1N];
      if (d >= IN_) atomicAdd(&cnt_ke[d - IN_], 1);
    } else {
      int d = ekdst[i - E1N - E2N];
      if (d < IN_) atomicAdd(&cnt_ek[d], 1);
    }
    return;
  }

  // ---- gemm path ----
  __shared__ short sW[32768];   // 64 KB: hi then lo frags
  const float *h1, *h2, *avec;
  unsigned* zb;
  float *ssrc, *sdst;
  const short* wf;
  int split, rows, rel;
  if (bid < NB0) {
    rel = bid; rows = KN; split = KN; h1 = kn; h2 = kn;
    wf = wfr; avec = a_dir; zb = zb_dir; ssrc = sds; sdst = sdd;
  } else if (bid < NB0 + NB1) {
    rel = bid - NB0; rows = NN; split = IN_; h1 = ex; h2 = kn;
    wf = wfr + 32768; avec = a_ke; zb = zb_ke; ssrc = sks; sdst = skd;
  } else {
    rel = bid - NB0 - NB1; rows = NN; split = IN_; h1 = ex; h2 = kn;
    wf = wfr + 65536; avec = a_ek; zb = zb_ek; ssrc = ses; sdst = sed;
  }

  {
    const int4* gs = (const int4*)wf;
    int4* ls = (int4*)sW;
#pragma unroll
    for (int it = 0; it < 16; ++it) ls[it * 256 + tid] = gs[it * 256 + tid];
  }
  __syncthreads();

  const int lane = tid & 63;
  const int wv = tid >> 6;
  const int q = lane >> 4;
  const int m = lane & 15;
  const int r = rel * 64 + wv * 16 + m;
  const int rc = (r < rows) ? r : (rows - 1);
  const float* hp = (rc < split) ? (h1 + (size_t)rc * 128)
                                 : (h2 + (size_t)(rc - split) * 128);

  floatx4 acc[8];
#pragma unroll
  for (int t = 0; t < 8; ++t) { acc[t][0] = 0.f; acc[t][1] = 0.f; acc[t][2] = 0.f; acc[t][3] = 0.f; }

#pragma unroll
  for (int chunk = 0; chunk < 4; ++chunk) {
    float4 v0 = *(const float4*)(hp + chunk * 32 + q * 8);
    float4 v1 = *(const float4*)(hp + chunk * 32 + q * 8 + 4);
    float vs[8] = {v0.x, v0.y, v0.z, v0.w, v1.x, v1.y, v1.z, v1.w};
    bf16x8 ahi, alo;
#pragma unroll
    for (int j = 0; j < 8; ++j) {
      unsigned hb = f2bf(vs[j]);
      ahi[j] = (short)hb;
      alo[j] = (short)f2bf(vs[j] - __uint_as_float(hb << 16));
    }
#pragma unroll
    for (int t = 0; t < 8; ++t) {
      bf16x8 bh = *(const bf16x8*)&sW[((t * 4 + chunk) * 64 + lane) * 8];
      bf16x8 bl = *(const bf16x8*)&sW[16384 + ((t * 4 + chunk) * 64 + lane) * 8];
      acc[t] = __builtin_amdgcn_mfma_f32_16x16x32_bf16(bh, ahi, acc[t], 0, 0, 0);
      acc[t] = __builtin_amdgcn_mfma_f32_16x16x32_bf16(bl, ahi, acc[t], 0, 0, 0);
      acc[t] = __builtin_amdgcn_mfma_f32_16x16x32_bf16(bh, alo, acc[t], 0, 0, 0);
    }
  }

  if (r < rows) {
    unsigned* zrow = zb + (size_t)r * 64;
#pragma unroll
    for (int t = 0; t < 8; ++t) {
      uint2 pk;
      pk.x = packbf(acc[t][0], acc[t][1]);
      pk.y = packbf(acc[t][2], acc[t][3]);
      *(uint2*)(zrow + t * 8 + q * 2) = pk;
    }
  }
  float d1 = 0.f, d2 = 0.f;
#pragma unroll
  for (int t = 0; t < 8; ++t) {
    float4 wa = *(const float4*)(avec + t * 16 + q * 4);
    float4 wb = *(const float4*)(avec + 128 + t * 16 + q * 4);
    d1 += acc[t][0] * wa.x + acc[t][1] * wa.y + acc[t][2] * wa.z + acc[t][3] * wa.w;
    d2 += acc[t][0] * wb.x + acc[t][1] * wb.y + acc[t][2] * wb.z + acc[t][3] * wb.w;
  }
  d1 += __shfl_xor(d1, 16, 64); d1 += __shfl_xor(d1, 32, 64);
  d2 += __shfl_xor(d2, 16, 64); d2 += __shfl_xor(d2, 32, 64);
  if (q == 0 && r < rows) { ssrc[r] = d1; sdst[r] = d2; }
}

// 3 independent single-block exclusive scans, shuffle-based
__global__ __launch_bounds__(1024) void scan3(
    const int* __restrict__ c0, int* __restrict__ o0, int n0,
    const int* __restrict__ c1, int* __restrict__ o1, int n1,
    const int* __restrict__ c2, int* __restrict__ o2, int n2)
{
  const int* cnt; int* off; int n;
  if (blockIdx.x == 0)      { cnt = c0; off = o0; n = n0; }
  else if (blockIdx.x == 1) { cnt = c1; off = o1; n = n1; }
  else                      { cnt = c2; off = o2; n = n2; }

  __shared__ int wsum[16];
  const int tid = threadIdx.x, lane = tid & 63, wv = tid >> 6;
  int carry = 0;
  for (int base = 0; base < n; base += 4096) {
    int i0 = base + tid * 4;
    int v[4];
#pragma unroll
    for (int j = 0; j < 4; ++j) v[j] = (i0 + j < n) ? cnt[i0 + j] : 0;
    int s = v[0] + v[1] + v[2] + v[3];
    int x = s;
#pragma unroll
    for (int o = 1; o < 64; o <<= 1) {
      int t = __shfl_up(x, o, 64);
      if (lane >= o) x += t;
    }
    if (lane == 63) wsum[wv] = x;
    __syncthreads();
    if (tid < 16) {
      int y = wsum[tid];
#pragma unroll
      for (int o = 1; o < 16; o <<= 1) {
        int t = __shfl_up(y, o, 16);
        if ((tid & 15) >= o) y += t;
      }
      wsum[tid] = y;
    }
    __syncthreads();
    int wbase = wv ? wsum[wv - 1] : 0;
    int total = wsum[15];
    int run = carry + wbase + x - s;
#pragma unroll
    for (int j = 0; j < 4; ++j) {
      if (i0 + j < n) off[i0 + j] = run;
      run += v[j];
    }
    carry += total;
    __syncthreads();
  }
  if (tid == 0) off[n] = carry;
}

// store (src, esc = ssrc[src]) per edge -> gather reads scores linearly
__global__ __launch_bounds__(256) void fill_edges(
    const int* __restrict__ dsrc, const int* __restrict__ ddst,
    const int* __restrict__ kesrc, const int* __restrict__ kedst,
    const int* __restrict__ eksrc, const int* __restrict__ ekdst,
    const float* __restrict__ sds, const float* __restrict__ sks, const float* __restrict__ ses,
    const int* __restrict__ off_dir, int* __restrict__ cur_dir, int2* __restrict__ ep_dir,
    const int* __restrict__ off_ke,  int* __restrict__ cur_ke,  int2* __restrict__ ep_ke,
    const int* __restrict__ off_ek,  int* __restrict__ cur_ek,  int2* __restrict__ ep_ek)
{
  int i = blockIdx.x * 256 + threadIdx.x;
  if (i < E1N) {
    int d = ddst[i];
    int s = dsrc[i];
    int pos = off_dir[d] + atomicAdd(&cur_dir[d], 1);
    ep_dir[pos] = make_int2(s, __float_as_int(sds[s]));
  } else if (i < E1N + E2N) {
    int e = i - E1N;
    int d = kedst[e];
    if (d >= IN_) {
      int seg = d - IN_;
      int s = kesrc[e];
      int pos = off_ke[seg] + atomicAdd(&cur_ke[seg], 1);
      ep_ke[pos] = make_int2(s, __float_as_int(sks[s]));
    }
  } else {
    int e = i - E1N - E2N;
    int d = ekdst[e];
    if (d < IN_) {
      int s = eksrc[e];
      int pos = off_ek[d] + atomicAdd(&cur_ek[d], 1);
      ep_ek[pos] = make_int2(s, __float_as_int(ses[s]));
    }
  }
}

// One wave per dst segment, SINGLE pass: accumulate unnormalized exp-weighted
// rows + den simultaneously, scale by 1/den at the end (m=0 softmax, exact).
// 4 groups x 16 lanes; each group: one bf16 row / iter (16B/lane), 2x unroll.
__global__ __launch_bounds__(256) void gat_gather(
    const int* __restrict__ off_dir, const int2* __restrict__ ep_dir,
    const float* __restrict__ sdd, const unsigned* __restrict__ zb_dir, float* __restrict__ A,
    const int* __restrict__ off_ke, const int2* __restrict__ ep_ke,
    const float* __restrict__ skd, const unsigned* __restrict__ zb_ke, float* __restrict__ Bm,
    const int* __restrict__ off_ek, const int2* __restrict__ ep_ek,
    const float* __restrict__ sed, const unsigned* __restrict__ zb_ek, float* __restrict__ Cout)
{
  int w = (blockIdx.x * 256 + threadIdx.x) >> 6;
  int lane = threadIdx.x & 63;
  int gid = lane >> 4, gl = lane & 15;
  const int* off; const int2* ep;
  const float* sD;
  const unsigned* zb;
  float* out;
  int seg, node;
  if (w < KN)                { seg = w;          node = seg;       off = off_dir; ep = ep_dir; sD = sdd; zb = zb_dir; out = A; }
  else if (w < 2 * KN)       { seg = w - KN;     node = seg + IN_; off = off_ke;  ep = ep_ke;  sD = skd; zb = zb_ke;  out = Bm; }
  else if (w < 2 * KN + IN_) { seg = w - 2 * KN; node = seg;       off = off_ek;  ep = ep_ek;  sD = sed; zb = zb_ek;  out = Cout; }
  else return;

  int b = off[seg], e = off[seg + 1];
  float av[8];
#pragma unroll
  for (int k = 0; k < 8; ++k) av[k] = 0.f;
  float den = 0.f;

  if (e > b) {
    float sd = sD[node];
    int i = b + gid;
    for (; i + 4 < e; i += 8) {
      int2 p1 = ep[i], p2 = ep[i + 4];
      float x1 = __int_as_float(p1.y) + sd; x1 = (x1 > 0.f) ? x1 : 0.01f * x1;
      float x2 = __int_as_float(p2.y) + sd; x2 = (x2 > 0.f) ? x2 : 0.01f * x2;
      float w1 = __expf(x1), w2 = __expf(x2);
      uint4 za = *(const uint4*)(zb + (size_t)p1.x * 64 + gl * 4);
      uint4 zc = *(const uint4*)(zb + (size_t)p2.x * 64 + gl * 4);
      den += w1 + w2;
      av[0] += w1 * bf_lo(za.x); av[1] += w1 * bf_hi(za.x);
      av[2] += w1 * bf_lo(za.y); av[3] += w1 * bf_hi(za.y);
      av[4] += w1 * bf_lo(za.z); av[5] += w1 * bf_hi(za.z);
      av[6] += w1 * bf_lo(za.w); av[7] += w1 * bf_hi(za.w);
      av[0] += w2 * bf_lo(zc.x); av[1] += w2 * bf_hi(zc.x);
      av[2] += w2 * bf_lo(zc.y); av[3] += w2 * bf_hi(zc.y);
      av[4] += w2 * bf_lo(zc.z); av[5] += w2 * bf_hi(zc.z);
      av[6] += w2 * bf_lo(zc.w); av[7] += w2 * bf_hi(zc.w);
    }
    if (i < e) {
      int2 p1 = ep[i];
      float x1 = __int_as_float(p1.y) + sd; x1 = (x1 > 0.f) ? x1 : 0.01f * x1;
      float w1 = __expf(x1);
      uint4 za = *(const uint4*)(zb + (size_t)p1.x * 64 + gl * 4);
      den += w1;
      av[0] += w1 * bf_lo(za.x); av[1] += w1 * bf_hi(za.x);
      av[2] += w1 * bf_lo(za.y); av[3] += w1 * bf_hi(za.y);
      av[4] += w1 * bf_lo(za.z); av[5] += w1 * bf_hi(za.z);
      av[6] += w1 * bf_lo(za.w); av[7] += w1 * bf_hi(za.w);
    }
    // cross-group reduce (groups hold disjoint edge subsets; within-group lanes identical den)
    den += __shfl_xor(den, 16, 64);
    den += __shfl_xor(den, 32, 64);
#pragma unroll
    for (int k = 0; k < 8; ++k) {
      av[k] += __shfl_xor(av[k], 16, 64);
      av[k] += __shfl_xor(av[k], 32, 64);
    }
    float inv = 1.f / den;
#pragma unroll
    for (int k = 0; k < 8; ++k) av[k] *= inv;
  }

  if (gid == 0) {
    float* op = out + (size_t)seg * 128 + gl * 8;
    *(float4*)op       = make_float4(av[0], av[1], av[2], av[3]);
    *(float4*)(op + 4) = make_float4(av[4], av[5], av[6], av[7]);
  }
}

// rel-gemm on Am and Bm rows simultaneously + tanh/w2 scores + softmax + combine.
__global__ __launch_bounds__(256, 2) void relgemm_combine(
    const float* __restrict__ Am, const float* __restrict__ Bm,
    const short* __restrict__ wfr_rel,
    const float* __restrict__ rb1, const float* __restrict__ rw2,
    float* __restrict__ out)
{
  __shared__ short sW[32768];
  const int tid = threadIdx.x;
  {
    const int4* gs = (const int4*)wfr_rel;
    int4* ls = (int4*)sW;
#pragma unroll
    for (int it = 0; it < 16; ++it) ls[it * 256 + tid] = gs[it * 256 + tid];
  }
  __syncthreads();

  const int lane = tid & 63;
  const int wv = tid >> 6;
  const int q = lane >> 4;
  const int m = lane & 15;
  const int r = blockIdx.x * 64 + wv * 16 + m;
  const int rc = (r < KN) ? r : (KN - 1);
  const float* hA = Am + (size_t)rc * 128;
  const float* hB = Bm + (size_t)rc * 128;

  floatx4 accA[8], accB[8];
#pragma unroll
  for (int t = 0; t < 8; ++t) {
    accA[t][0]=0.f; accA[t][1]=0.f; accA[t][2]=0.f; accA[t][3]=0.f;
    accB[t][0]=0.f; accB[t][1]=0.f; accB[t][2]=0.f; accB[t][3]=0.f;
  }

#pragma unroll
  for (int chunk = 0; chunk < 4; ++chunk) {
    float4 a0 = *(const float4*)(hA + chunk * 32 + q * 8);
    float4 a1 = *(const float4*)(hA + chunk * 32 + q * 8 + 4);
    float4 b0 = *(const float4*)(hB + chunk * 32 + q * 8);
    float4 b1 = *(const float4*)(hB + chunk * 32 + q * 8 + 4);
    float as[8] = {a0.x, a0.y, a0.z, a0.w, a1.x, a1.y, a1.z, a1.w};
    float bs[8] = {b0.x, b0.y, b0.z, b0.w, b1.x, b1.y, b1.z, b1.w};
    bf16x8 ahiA, aloA, ahiB, aloB;
#pragma unroll
    for (int j = 0; j < 8; ++j) {
      unsigned ha = f2bf(as[j]);
      ahiA[j] = (short)ha;
      aloA[j] = (short)f2bf(as[j] - __uint_as_float(ha << 16));
      unsigned hb = f2bf(bs[j]);
      ahiB[j] = (short)hb;
      aloB[j] = (short)f2bf(bs[j] - __uint_as_float(hb << 16));
    }
#pragma unroll
    for (int t = 0; t < 8; ++t) {
      bf16x8 bh = *(const bf16x8*)&sW[((t * 4 + chunk) * 64 + lane) * 8];
      bf16x8 bl = *(const bf16x8*)&sW[16384 + ((t * 4 + chunk) * 64 + lane) * 8];
      accA[t] = __builtin_amdgcn_mfma_f32_16x16x32_bf16(bh, ahiA, accA[t], 0, 0, 0);
      accA[t] = __builtin_amdgcn_mfma_f32_16x16x32_bf16(bl, ahiA, accA[t], 0, 0, 0);
      accA[t] = __builtin_amdgcn_mfma_f32_16x16x32_bf16(bh, aloA, accA[t], 0, 0, 0);
      accB[t] = __builtin_amdgcn_mfma_f32_16x16x32_bf16(bh, ahiB, accB[t], 0, 0, 0);
      accB[t] = __builtin_amdgcn_mfma_f32_16x16x32_bf16(bl, ahiB, accB[t], 0, 0, 0);
      accB[t] = __builtin_amdgcn_mfma_f32_16x16x32_bf16(bh, aloB, accB[t], 0, 0, 0);
    }
  }

  float p1 = 0.f, p2 = 0.f;
#pragma unroll
  for (int t = 0; t < 8; ++t) {
    float4 bb = *(const float4*)(rb1 + t * 16 + q * 4);
    float4 ww = *(const float4*)(rw2 + t * 16 + q * 4);
    p1 += tanhf(accA[t][0] + bb.x) * ww.x + tanhf(accA[t][1] + bb.y) * ww.y +
          tanhf(accA[t][2] + bb.z) * ww.z + tanhf(accA[t][3] + bb.w) * ww.w;
    p2 += tanhf(accB[t][0] + bb.x) * ww.x + tanhf(accB[t][1] + bb.y) * ww.y +
          tanhf(accB[t][2] + bb.z) * ww.z + tanhf(accB[t][3] + bb.w) * ww.w;
  }
  p1 += __shfl_xor(p1, 16, 64); p1 += __shfl_xor(p1, 32, 64);
  p2 += __shfl_xor(p2, 16, 64); p2 += __shfl_xor(p2, 32, 64);

  float mx = fmaxf(p1, p2);
  float e1 = __expf(p1 - mx), e2 = __expf(p2 - mx);
  float al = e1 / (e1 + e2), be = e2 / (e1 + e2);

  if (r < KN) {
#pragma unroll
    for (int t = 0; t < 8; ++t) {
      int col = t * 16 + q * 4;
      float4 avv = *(const float4*)(Am + (size_t)r * 128 + col);
      float4 bvv = *(const float4*)(Bm + (size_t)r * 128 + col);
      *(float4*)(out + (size_t)r * 128 + col) =
          make_float4(al * avv.x + be * bvv.x, al * avv.y + be * bvv.y,
                      al * avv.z + be * bvv.z, al * avv.w + be * bvv.w);
    }
  }
}

extern "C" void kernel_launch(void* const* d_in, const int* in_sizes, int n_in,
                              void* d_out, int out_size, void* d_ws, size_t ws_size,
                              hipStream_t stream) {
  const float* kn    = (const float*)d_in[0];
  const float* ex    = (const float*)d_in[1];
  const float* W_dir = (const float*)d_in[2];
  const float* a_dir = (const float*)d_in[3];
  const float* W_ke  = (const float*)d_in[4];
  const float* a_ke  = (const float*)d_in[5];
  const float* W_ek  = (const float*)d_in[6];
  const float* a_ek  = (const float*)d_in[7];
  const float* rW1   = (const float*)d_in[8];
  const float* rb1   = (const float*)d_in[9];
  const float* rw2   = (const float*)d_in[10];
  const int* dsrc    = (const int*)d_in[11];
  const int* ddst    = (const int*)d_in[12];
  const int* kesrc   = (const int*)d_in[13];
  const int* kedst   = (const int*)d_in[14];
  const int* eksrc   = (const int*)d_in[15];
  const int* ekdst   = (const int*)d_in[16];
  float* out = (float*)d_out;

  char* p = (char*)d_ws;
  auto alloc = [&](size_t bytes) {
    char* r = p;
    p += (bytes + 255) & ~(size_t)255;
    return r;
  };
  unsigned* zb_dir = (unsigned*)alloc((size_t)KN * 64 * 4);
  unsigned* zb_ke  = (unsigned*)alloc((size_t)NN * 64 * 4);
  unsigned* zb_ek  = (unsigned*)alloc((size_t)NN * 64 * 4);
  float* Am    = (float*)alloc((size_t)KN * 128 * 4);
  float* Bmat  = (float*)alloc((size_t)KN * 128 * 4);
  short* wfr   = (short*)alloc((size_t)4 * 32768 * 2);
  float* sds = (float*)alloc(KN * 4);
  float* sdd = (float*)alloc(KN * 4);
  float* sks = (float*)alloc(NN * 4);
  float* skd = (float*)alloc(NN * 4);
  float* ses = (float*)alloc(NN * 4);
  float* sed = (float*)alloc(NN * 4);
  int* cntblk  = (int*)alloc((size_t)(4 * KN + 2 * IN_) * 4);
  int* cnt_dir = cntblk;
  int* cur_dir = cntblk + KN;
  int* cnt_ke  = cntblk + 2 * KN;
  int* cur_ke  = cntblk + 3 * KN;
  int* cnt_ek  = cntblk + 4 * KN;
  int* cur_ek  = cntblk + 4 * KN + IN_;
  int* off_dir = (int*)alloc((KN + 1) * 4);
  int* off_ke  = (int*)alloc((KN + 1) * 4);
  int* off_ek  = (int*)alloc((IN_ + 1) * 4);
  int2* ep_dir = (int2*)alloc((size_t)E1N * 8);
  int2* ep_ke  = (int2*)alloc((size_t)E2N * 8);
  int2* ep_ek  = (int2*)alloc((size_t)E2N * 8);

  hipMemsetAsync(cntblk, 0, (size_t)(4 * KN + 2 * IN_) * 4, stream);

  wconv<<<32, 256, 0, stream>>>(W_dir, W_ke, W_ek, rW1, wfr);

  fused_gemm_count<<<CB0 + NCNT, 256, 0, stream>>>(
      kn, ex, wfr, a_dir, a_ke, a_ek,
      zb_dir, zb_ke, zb_ek,
      sds, sdd, sks, skd, ses, sed,
      ddst, kedst, ekdst, cnt_dir, cnt_ke, cnt_ek);

  scan3<<<3, 1024, 0, stream>>>(cnt_dir, off_dir, KN, cnt_ke, off_ke, KN, cnt_ek, off_ek, IN_);

  fill_edges<<<(E1N + 2 * E2N + 255) / 256, 256, 0, stream>>>(
      dsrc, ddst, kesrc, kedst, eksrc, ekdst,
      sds, sks, ses,
      off_dir, cur_dir, ep_dir, off_ke, cur_ke, ep_ke, off_ek, cur_ek, ep_ek);

  gat_gather<<<(2 * KN + IN_ + 3) / 4, 256, 0, stream>>>(
      off_dir, ep_dir, sdd, zb_dir, Am,
      off_ke,  ep_ke,  skd, zb_ke,  Bmat,
      off_ek,  ep_ek,  sed, zb_ek,  out + (size_t)KN * 128);

  relgemm_combine<<<NB0, 256, 0, stream>>>(Am, Bmat, wfr + 3 * 32768, rb1, rw2, out);
}

// Round 5
// 333.528 us; speedup vs baseline: 1.9123x; 1.0029x over previous
//
#include <hip/hip_runtime.h>
#include <math.h>

#define KN   20000
#define IN_  50000
#define DD   128
#define NN   70000
#define E1N  320000
#define E2N  640000

// gemm3 tiles: 256 rows/block
#define NT0  79     // ceil(20000/256)
#define NT1  274    // ceil(70000/256)
#define NT2  274

typedef short bf16x8 __attribute__((ext_vector_type(8)));
typedef float floatx4 __attribute__((ext_vector_type(4)));

__device__ __forceinline__ unsigned f2bf(float x) {
  unsigned u = __float_as_uint(x);
  return (u + 0x7FFFu + ((u >> 16) & 1u)) >> 16;   // RNE
}
__device__ __forceinline__ unsigned packbf(float a, float b) {
  return f2bf(a) | (f2bf(b) << 16);
}
__device__ __forceinline__ float bf_lo(unsigned u) { return __uint_as_float(u << 16); }
__device__ __forceinline__ float bf_hi(unsigned u) { return __uint_as_float(u & 0xFFFF0000u); }

// Pre-convert 4 weight matrices into MFMA-fragment-ordered bf16 hi/lo arrays.
__global__ __launch_bounds__(256) void wconv(
    const float* __restrict__ W0, const float* __restrict__ W1,
    const float* __restrict__ W2, const float* __restrict__ W3,
    short* __restrict__ wfr)
{
  int b = blockIdx.x;
  int wsel = b >> 3;
  const float* W = (wsel == 0) ? W0 : (wsel == 1) ? W1 : (wsel == 2) ? W2 : W3;
  int fi = (b & 7) * 256 + threadIdx.x;      // 0..2047
  int l = fi & 63, chunk = (fi >> 6) & 3, t = fi >> 8;
  int col = t * 16 + (l & 15);
  int kbase = chunk * 32 + (l >> 4) * 8;
  bf16x8 hv, lv;
#pragma unroll
  for (int j = 0; j < 8; ++j) {
    float v = W[(kbase + j) * 128 + col];
    unsigned hb = f2bf(v);
    hv[j] = (short)hb;
    lv[j] = (short)f2bf(v - __uint_as_float(hb << 16));
  }
  short* dst = wfr + wsel * 32768;
  *(bf16x8*)&dst[fi * 8] = hv;
  *(bf16x8*)&dst[16384 + fi * 8] = lv;
}

// standalone, zero LDS -> full occupancy
__global__ __launch_bounds__(256) void count_edges(
    const int* __restrict__ ddst, const int* __restrict__ kedst, const int* __restrict__ ekdst,
    int* __restrict__ cnt_dir, int* __restrict__ cnt_ke, int* __restrict__ cnt_ek)
{
  int i = blockIdx.x * 256 + threadIdx.x;
  if (i < E1N) {
    atomicAdd(&cnt_dir[ddst[i]], 1);
  } else if (i < E1N + E2N) {
    int d = kedst[i - E1N];
    if (d >= IN_) atomicAdd(&cnt_ke[d - IN_], 1);
  } else {
    int d = ekdst[i - E1N - E2N];
    if (d < IN_) atomicAdd(&cnt_ek[d], 1);
  }
}

// 3x MFMA gemms, 256 rows/block (4 sub-tiles of 64 per W staging).
__global__ __launch_bounds__(256, 2) void gemm3(
    const float* __restrict__ kn, const float* __restrict__ ex,
    const short* __restrict__ wfr,
    const float* __restrict__ a_dir, const float* __restrict__ a_ke, const float* __restrict__ a_ek,
    unsigned* __restrict__ zb_dir, unsigned* __restrict__ zb_ke, unsigned* __restrict__ zb_ek,
    float* __restrict__ sds, float* __restrict__ sdd,
    float* __restrict__ sks, float* __restrict__ skd,
    float* __restrict__ ses, float* __restrict__ sed)
{
  __shared__ short sW[32768];   // 64 KB: hi then lo frags
  const int bid = blockIdx.x;
  const int tid = threadIdx.x;

  const float *h1, *h2, *avec;
  unsigned* zb;
  float *ssrc, *sdst;
  const short* wf;
  int split, rows, tile;
  if (bid < NT0) {
    tile = bid; rows = KN; split = KN; h1 = kn; h2 = kn;
    wf = wfr; avec = a_dir; zb = zb_dir; ssrc = sds; sdst = sdd;
  } else if (bid < NT0 + NT1) {
    tile = bid - NT0; rows = NN; split = IN_; h1 = ex; h2 = kn;
    wf = wfr + 32768; avec = a_ke; zb = zb_ke; ssrc = sks; sdst = skd;
  } else {
    tile = bid - NT0 - NT1; rows = NN; split = IN_; h1 = ex; h2 = kn;
    wf = wfr + 65536; avec = a_ek; zb = zb_ek; ssrc = ses; sdst = sed;
  }

  {
    const int4* gs = (const int4*)wf;
    int4* ls = (int4*)sW;
#pragma unroll
    for (int it = 0; it < 16; ++it) ls[it * 256 + tid] = gs[it * 256 + tid];
  }
  __syncthreads();

  const int lane = tid & 63;
  const int wv = tid >> 6;
  const int q = lane >> 4;
  const int m = lane & 15;

#pragma unroll
  for (int sub = 0; sub < 4; ++sub) {
    const int r0w = tile * 256 + sub * 64 + wv * 16;   // wave-uniform
    if (r0w >= rows) continue;
    const int r = r0w + m;
    const int rc = (r < rows) ? r : (rows - 1);
    const float* hp = (rc < split) ? (h1 + (size_t)rc * 128)
                                   : (h2 + (size_t)(rc - split) * 128);

    floatx4 acc[8];
#pragma unroll
    for (int t = 0; t < 8; ++t) { acc[t][0]=0.f; acc[t][1]=0.f; acc[t][2]=0.f; acc[t][3]=0.f; }

#pragma unroll
    for (int chunk = 0; chunk < 4; ++chunk) {
      float4 v0 = *(const float4*)(hp + chunk * 32 + q * 8);
      float4 v1 = *(const float4*)(hp + chunk * 32 + q * 8 + 4);
      float vs[8] = {v0.x, v0.y, v0.z, v0.w, v1.x, v1.y, v1.z, v1.w};
      bf16x8 ahi, alo;
#pragma unroll
      for (int j = 0; j < 8; ++j) {
        unsigned hb = f2bf(vs[j]);
        ahi[j] = (short)hb;
        alo[j] = (short)f2bf(vs[j] - __uint_as_float(hb << 16));
      }
#pragma unroll
      for (int t = 0; t < 8; ++t) {
        bf16x8 bh = *(const bf16x8*)&sW[((t * 4 + chunk) * 64 + lane) * 8];
        bf16x8 bl = *(const bf16x8*)&sW[16384 + ((t * 4 + chunk) * 64 + lane) * 8];
        acc[t] = __builtin_amdgcn_mfma_f32_16x16x32_bf16(bh, ahi, acc[t], 0, 0, 0);
        acc[t] = __builtin_amdgcn_mfma_f32_16x16x32_bf16(bl, ahi, acc[t], 0, 0, 0);
        acc[t] = __builtin_amdgcn_mfma_f32_16x16x32_bf16(bh, alo, acc[t], 0, 0, 0);
      }
    }

    if (r < rows) {
      unsigned* zrow = zb + (size_t)r * 64;
#pragma unroll
      for (int t = 0; t < 8; ++t) {
        uint2 pk;
        pk.x = packbf(acc[t][0], acc[t][1]);
        pk.y = packbf(acc[t][2], acc[t][3]);
        *(uint2*)(zrow + t * 8 + q * 2) = pk;
      }
    }
    float d1 = 0.f, d2 = 0.f;
#pragma unroll
    for (int t = 0; t < 8; ++t) {
      float4 wa = *(const float4*)(avec + t * 16 + q * 4);
      float4 wb = *(const float4*)(avec + 128 + t * 16 + q * 4);
      d1 += acc[t][0] * wa.x + acc[t][1] * wa.y + acc[t][2] * wa.z + acc[t][3] * wa.w;
      d2 += acc[t][0] * wb.x + acc[t][1] * wb.y + acc[t][2] * wb.z + acc[t][3] * wb.w;
    }
    d1 += __shfl_xor(d1, 16, 64); d1 += __shfl_xor(d1, 32, 64);
    d2 += __shfl_xor(d2, 16, 64); d2 += __shfl_xor(d2, 32, 64);
    if (q == 0 && r < rows) { ssrc[r] = d1; sdst[r] = d2; }
  }
}

// CSR allocation without ordered scan: wave shuffle-scan + 1 atomic/wave.
__global__ __launch_bounds__(256) void alloc_off(
    const int* __restrict__ cnt_dir, int* __restrict__ st_dir,
    const int* __restrict__ cnt_ke,  int* __restrict__ st_ke,
    const int* __restrict__ cnt_ek,  int* __restrict__ st_ek,
    int* __restrict__ totals)
{
  int b = blockIdx.x;
  const int* cnt; int* st; int* tot; int n, i0;
  if (b < 79)       { cnt = cnt_dir; st = st_dir; tot = totals + 0; n = KN;  i0 = b * 256; }
  else if (b < 158) { cnt = cnt_ke;  st = st_ke;  tot = totals + 1; n = KN;  i0 = (b - 79) * 256; }
  else              { cnt = cnt_ek;  st = st_ek;  tot = totals + 2; n = IN_; i0 = (b - 158) * 256; }
  int i = i0 + threadIdx.x;
  int lane = threadIdx.x & 63;
  int v = (i < n) ? cnt[i] : 0;
  int x = v;
#pragma unroll
  for (int o = 1; o < 64; o <<= 1) {
    int t = __shfl_up(x, o, 64);
    if (lane >= o) x += t;
  }
  int base = 0;
  if (lane == 63) base = atomicAdd(tot, x);
  base = __shfl(base, 63, 64);
  if (i < n) st[i] = base + x - v;
}

// store (src, esc = ssrc[src]) per edge -> gather reads scores linearly
__global__ __launch_bounds__(256) void fill_edges(
    const int* __restrict__ dsrc, const int* __restrict__ ddst,
    const int* __restrict__ kesrc, const int* __restrict__ kedst,
    const int* __restrict__ eksrc, const int* __restrict__ ekdst,
    const float* __restrict__ sds, const float* __restrict__ sks, const float* __restrict__ ses,
    const int* __restrict__ st_dir, int* __restrict__ cur_dir, int2* __restrict__ ep_dir,
    const int* __restrict__ st_ke,  int* __restrict__ cur_ke,  int2* __restrict__ ep_ke,
    const int* __restrict__ st_ek,  int* __restrict__ cur_ek,  int2* __restrict__ ep_ek)
{
  int i = blockIdx.x * 256 + threadIdx.x;
  if (i < E1N) {
    int d = ddst[i];
    int s = dsrc[i];
    int pos = st_dir[d] + atomicAdd(&cur_dir[d], 1);
    ep_dir[pos] = make_int2(s, __float_as_int(sds[s]));
  } else if (i < E1N + E2N) {
    int e = i - E1N;
    int d = kedst[e];
    if (d >= IN_) {
      int seg = d - IN_;
      int s = kesrc[e];
      int pos = st_ke[seg] + atomicAdd(&cur_ke[seg], 1);
      ep_ke[pos] = make_int2(s, __float_as_int(sks[s]));
    }
  } else {
    int e = i - E1N - E2N;
    int d = ekdst[e];
    if (d < IN_) {
      int s = eksrc[e];
      int pos = st_ek[d] + atomicAdd(&cur_ek[d], 1);
      ep_ek[pos] = make_int2(s, __float_as_int(ses[s]));
    }
  }
}

// One wave per dst segment, single pass (m=0 softmax).
__global__ __launch_bounds__(256) void gat_gather(
    const int* __restrict__ st_dir, const int* __restrict__ cnt_dir, const int2* __restrict__ ep_dir,
    const float* __restrict__ sdd, const unsigned* __restrict__ zb_dir, float* __restrict__ A,
    const int* __restrict__ st_ke, const int* __restrict__ cnt_ke, const int2* __restrict__ ep_ke,
    const float* __restrict__ skd, const unsigned* __restrict__ zb_ke, float* __restrict__ Bm,
    const int* __restrict__ st_ek, const int* __restrict__ cnt_ek, const int2* __restrict__ ep_ek,
    const float* __restrict__ sed, const unsigned* __restrict__ zb_ek, float* __restrict__ Cout)
{
  int w = (blockIdx.x * 256 + threadIdx.x) >> 6;
  int lane = threadIdx.x & 63;
  int gid = lane >> 4, gl = lane & 15;
  const int *st, *cn; const int2* ep;
  const float* sD;
  const unsigned* zb;
  float* out;
  int seg, node;
  if (w < KN)                { seg = w;          node = seg;       st = st_dir; cn = cnt_dir; ep = ep_dir; sD = sdd; zb = zb_dir; out = A; }
  else if (w < 2 * KN)       { seg = w - KN;     node = seg + IN_; st = st_ke;  cn = cnt_ke;  ep = ep_ke;  sD = skd; zb = zb_ke;  out = Bm; }
  else if (w < 2 * KN + IN_) { seg = w - 2 * KN; node = seg;       st = st_ek;  cn = cnt_ek;  ep = ep_ek;  sD = sed; zb = zb_ek;  out = Cout; }
  else return;

  int b = st[seg], e = b + cn[seg];
  float av[8];
#pragma unroll
  for (int k = 0; k < 8; ++k) av[k] = 0.f;
  float den = 0.f;

  if (e > b) {
    float sd = sD[node];
    int i = b + gid;
    for (; i + 4 < e; i += 8) {
      int2 p1 = ep[i], p2 = ep[i + 4];
      float x1 = __int_as_float(p1.y) + sd; x1 = (x1 > 0.f) ? x1 : 0.01f * x1;
      float x2 = __int_as_float(p2.y) + sd; x2 = (x2 > 0.f) ? x2 : 0.01f * x2;
      float w1 = __expf(x1), w2 = __expf(x2);
      uint4 za = *(const uint4*)(zb + (size_t)p1.x * 64 + gl * 4);
      uint4 zc = *(const uint4*)(zb + (size_t)p2.x * 64 + gl * 4);
      den += w1 + w2;
      av[0] += w1 * bf_lo(za.x); av[1] += w1 * bf_hi(za.x);
      av[2] += w1 * bf_lo(za.y); av[3] += w1 * bf_hi(za.y);
      av[4] += w1 * bf_lo(za.z); av[5] += w1 * bf_hi(za.z);
      av[6] += w1 * bf_lo(za.w); av[7] += w1 * bf_hi(za.w);
      av[0] += w2 * bf_lo(zc.x); av[1] += w2 * bf_hi(zc.x);
      av[2] += w2 * bf_lo(zc.y); av[3] += w2 * bf_hi(zc.y);
      av[4] += w2 * bf_lo(zc.z); av[5] += w2 * bf_hi(zc.z);
      av[6] += w2 * bf_lo(zc.w); av[7] += w2 * bf_hi(zc.w);
    }
    if (i < e) {
      int2 p1 = ep[i];
      float x1 = __int_as_float(p1.y) + sd; x1 = (x1 > 0.f) ? x1 : 0.01f * x1;
      float w1 = __expf(x1);
      uint4 za = *(const uint4*)(zb + (size_t)p1.x * 64 + gl * 4);
      den += w1;
      av[0] += w1 * bf_lo(za.x); av[1] += w1 * bf_hi(za.x);
      av[2] += w1 * bf_lo(za.y); av[3] += w1 * bf_hi(za.y);
      av[4] += w1 * bf_lo(za.z); av[5] += w1 * bf_hi(za.z);
      av[6] += w1 * bf_lo(za.w); av[7] += w1 * bf_hi(za.w);
    }
    den += __shfl_xor(den, 16, 64);
    den += __shfl_xor(den, 32, 64);
#pragma unroll
    for (int k = 0; k < 8; ++k) {
      av[k] += __shfl_xor(av[k], 16, 64);
      av[k] += __shfl_xor(av[k], 32, 64);
    }
    float inv = 1.f / den;
#pragma unroll
    for (int k = 0; k < 8; ++k) av[k] *= inv;
  }

  if (gid == 0) {
    float* op = out + (size_t)seg * 128 + gl * 8;
    *(float4*)op       = make_float4(av[0], av[1], av[2], av[3]);
    *(float4*)(op + 4) = make_float4(av[4], av[5], av[6], av[7]);
  }
}

// rel-gemm on Am and Bm rows + tanh/w2 scores + softmax + combine.
__global__ __launch_bounds__(256, 2) void relgemm_combine(
    const float* __restrict__ Am, const float* __restrict__ Bm,
    const short* __restrict__ wfr_rel,
    const float* __restrict__ rb1, const float* __restrict__ rw2,
    float* __restrict__ out)
{
  __shared__ short sW[32768];
  const int tid = threadIdx.x;
  {
    const int4* gs = (const int4*)wfr_rel;
    int4* ls = (int4*)sW;
#pragma unroll
    for (int it = 0; it < 16; ++it) ls[it * 256 + tid] = gs[it * 256 + tid];
  }
  __syncthreads();

  const int lane = tid & 63;
  const int wv = tid >> 6;
  const int q = lane >> 4;
  const int m = lane & 15;
  const int r = blockIdx.x * 64 + wv * 16 + m;
  const int rc = (r < KN) ? r : (KN - 1);
  const float* hA = Am + (size_t)rc * 128;
  const float* hB = Bm + (size_t)rc * 128;

  floatx4 accA[8], accB[8];
#pragma unroll
  for (int t = 0; t < 8; ++t) {
    accA[t][0]=0.f; accA[t][1]=0.f; accA[t][2]=0.f; accA[t][3]=0.f;
    accB[t][0]=0.f; accB[t][1]=0.f; accB[t][2]=0.f; accB[t][3]=0.f;
  }

#pragma unroll
  for (int chunk = 0; chunk < 4; ++chunk) {
    float4 a0 = *(const float4*)(hA + chunk * 32 + q * 8);
    float4 a1 = *(const float4*)(hA + chunk * 32 + q * 8 + 4);
    float4 b0 = *(const float4*)(hB + chunk * 32 + q * 8);
    float4 b1 = *(const float4*)(hB + chunk * 32 + q * 8 + 4);
    float as[8] = {a0.x, a0.y, a0.z, a0.w, a1.x, a1.y, a1.z, a1.w};
    float bs[8] = {b0.x, b0.y, b0.z, b0.w, b1.x, b1.y, b1.z, b1.w};
    bf16x8 ahiA, aloA, ahiB, aloB;
#pragma unroll
    for (int j = 0; j < 8; ++j) {
      unsigned ha = f2bf(as[j]);
      ahiA[j] = (short)ha;
      aloA[j] = (short)f2bf(as[j] - __uint_as_float(ha << 16));
      unsigned hb = f2bf(bs[j]);
      ahiB[j] = (short)hb;
      aloB[j] = (short)f2bf(bs[j] - __uint_as_float(hb << 16));
    }
#pragma unroll
    for (int t = 0; t < 8; ++t) {
      bf16x8 bh = *(const bf16x8*)&sW[((t * 4 + chunk) * 64 + lane) * 8];
      bf16x8 bl = *(const bf16x8*)&sW[16384 + ((t * 4 + chunk) * 64 + lane) * 8];
      accA[t] = __builtin_amdgcn_mfma_f32_16x16x32_bf16(bh, ahiA, accA[t], 0, 0, 0);
      accA[t] = __builtin_amdgcn_mfma_f32_16x16x32_bf16(bl, ahiA, accA[t], 0, 0, 0);
      accA[t] = __builtin_amdgcn_mfma_f32_16x16x32_bf16(bh, aloA, accA[t], 0, 0, 0);
      accB[t] = __builtin_amdgcn_mfma_f32_16x16x32_bf16(bh, ahiB, accB[t], 0, 0, 0);
      accB[t] = __builtin_amdgcn_mfma_f32_16x16x32_bf16(bl, ahiB, accB[t], 0, 0, 0);
      accB[t] = __builtin_amdgcn_mfma_f32_16x16x32_bf16(bh, aloB, accB[t], 0, 0, 0);
    }
  }

  float p1 = 0.f, p2 = 0.f;
#pragma unroll
  for (int t = 0; t < 8; ++t) {
    float4 bb = *(const float4*)(rb1 + t * 16 + q * 4);
    float4 ww = *(const float4*)(rw2 + t * 16 + q * 4);
    p1 += tanhf(accA[t][0] + bb.x) * ww.x + tanhf(accA[t][1] + bb.y) * ww.y +
          tanhf(accA[t][2] + bb.z) * ww.z + tanhf(accA[t][3] + bb.w) * ww.w;
    p2 += tanhf(accB[t][0] + bb.x) * ww.x + tanhf(accB[t][1] + bb.y) * ww.y +
          tanhf(accB[t][2] + bb.z) * ww.z + tanhf(accB[t][3] + bb.w) * ww.w;
  }
  p1 += __shfl_xor(p1, 16, 64); p1 += __shfl_xor(p1, 32, 64);
  p2 += __shfl_xor(p2, 16, 64); p2 += __shfl_xor(p2, 32, 64);

  float mx = fmaxf(p1, p2);
  float e1 = __expf(p1 - mx), e2 = __expf(p2 - mx);
  float al = e1 / (e1 + e2), be = e2 / (e1 + e2);

  if (r < KN) {
#pragma unroll
    for (int t = 0; t < 8; ++t) {
      int col = t * 16 + q * 4;
      float4 avv = *(const float4*)(Am + (size_t)r * 128 + col);
      float4 bvv = *(const float4*)(Bm + (size_t)r * 128 + col);
      *(float4*)(out + (size_t)r * 128 + col) =
          make_float4(al * avv.x + be * bvv.x, al * avv.y + be * bvv.y,
                      al * avv.z + be * bvv.z, al * avv.w + be * bvv.w);
    }
  }
}

extern "C" void kernel_launch(void* const* d_in, const int* in_sizes, int n_in,
                              void* d_out, int out_size, void* d_ws, size_t ws_size,
                              hipStream_t stream) {
  const float* kn    = (const float*)d_in[0];
  const float* ex    = (const float*)d_in[1];
  const float* W_dir = (const float*)d_in[2];
  const float* a_dir = (const float*)d_in[3];
  const float* W_ke  = (const float*)d_in[4];
  const float* a_ke  = (const float*)d_in[5];
  const float* W_ek  = (const float*)d_in[6];
  const float* a_ek  = (const float*)d_in[7];
  const float* rW1   = (const float*)d_in[8];
  const float* rb1   = (const float*)d_in[9];
  const float* rw2   = (const float*)d_in[10];
  const int* dsrc    = (const int*)d_in[11];
  const int* ddst    = (const int*)d_in[12];
  const int* kesrc   = (const int*)d_in[13];
  const int* kedst   = (const int*)d_in[14];
  const int* eksrc   = (const int*)d_in[15];
  const int* ekdst   = (const int*)d_in[16];
  float* out = (float*)d_out;

  char* p = (char*)d_ws;
  auto alloc = [&](size_t bytes) {
    char* r = p;
    p += (bytes + 255) & ~(size_t)255;
    return r;
  };
  unsigned* zb_dir = (unsigned*)alloc((size_t)KN * 64 * 4);
  unsigned* zb_ke  = (unsigned*)alloc((size_t)NN * 64 * 4);
  unsigned* zb_ek  = (unsigned*)alloc((size_t)NN * 64 * 4);
  float* Am    = (float*)alloc((size_t)KN * 128 * 4);
  float* Bmat  = (float*)alloc((size_t)KN * 128 * 4);
  short* wfr   = (short*)alloc((size_t)4 * 32768 * 2);
  float* sds = (float*)alloc(KN * 4);
  float* sdd = (float*)alloc(KN * 4);
  float* sks = (float*)alloc(NN * 4);
  float* skd = (float*)alloc(NN * 4);
  float* ses = (float*)alloc(NN * 4);
  float* sed = (float*)alloc(NN * 4);
  int* cntblk  = (int*)alloc((size_t)(4 * KN + 2 * IN_ + 64) * 4);
  int* cnt_dir = cntblk;
  int* cur_dir = cntblk + KN;
  int* cnt_ke  = cntblk + 2 * KN;
  int* cur_ke  = cntblk + 3 * KN;
  int* cnt_ek  = cntblk + 4 * KN;
  int* cur_ek  = cntblk + 4 * KN + IN_;
  int* totals  = cntblk + 4 * KN + 2 * IN_;
  int* st_dir = (int*)alloc(KN * 4);
  int* st_ke  = (int*)alloc(KN * 4);
  int* st_ek  = (int*)alloc(IN_ * 4);
  int2* ep_dir = (int2*)alloc((size_t)E1N * 8);
  int2* ep_ke  = (int2*)alloc((size_t)E2N * 8);
  int2* ep_ek  = (int2*)alloc((size_t)E2N * 8);

  hipMemsetAsync(cntblk, 0, (size_t)(4 * KN + 2 * IN_ + 64) * 4, stream);

  wconv<<<32, 256, 0, stream>>>(W_dir, W_ke, W_ek, rW1, wfr);

  count_edges<<<(E1N + 2 * E2N + 255) / 256, 256, 0, stream>>>(
      ddst, kedst, ekdst, cnt_dir, cnt_ke, cnt_ek);

  gemm3<<<NT0 + NT1 + NT2, 256, 0, stream>>>(
      kn, ex, wfr, a_dir, a_ke, a_ek,
      zb_dir, zb_ke, zb_ek,
      sds, sdd, sks, skd, ses, sed);

  alloc_off<<<354, 256, 0, stream>>>(cnt_dir, st_dir, cnt_ke, st_ke, cnt_ek, st_ek, totals);

  fill_edges<<<(E1N + 2 * E2N + 255) / 256, 256, 0, stream>>>(
      dsrc, ddst, kesrc, kedst, eksrc, ekdst,
      sds, sks, ses,
      st_dir, cur_dir, ep_dir, st_ke, cur_ke, ep_ke, st_ek, cur_ek, ep_ek);

  gat_gather<<<(2 * KN + IN_ + 3) / 4, 256, 0, stream>>>(
      st_dir, cnt_dir, ep_dir, sdd, zb_dir, Am,
      st_ke,  cnt_ke,  ep_ke,  skd, zb_ke,  Bmat,
      st_ek,  cnt_ek,  ep_ek,  sed, zb_ek,  out + (size_t)KN * 128);

  relgemm_combine<<<313, 256, 0, stream>>>(Am, Bmat, wfr + 3 * 32768, rb1, rw2, out);
}

// Round 6
// 283.637 us; speedup vs baseline: 2.2487x; 1.1759x over previous
//
#include <hip/hip_runtime.h>
#include <math.h>

#define KN   20000
#define IN_  50000
#define DD   128
#define NN   70000
#define E1N  320000
#define E2N  640000

// gemm3: 64 rows/block
#define GB0  313     // ceil(20000/64)
#define GB1  1094    // ceil(70000/64)
#define GB2  1094

typedef _Float16 f16x8 __attribute__((ext_vector_type(8)));
typedef float floatx4 __attribute__((ext_vector_type(4)));

__device__ __forceinline__ unsigned f2bf(float x) {
  unsigned u = __float_as_uint(x);
  return (u + 0x7FFFu + ((u >> 16) & 1u)) >> 16;   // RNE
}
__device__ __forceinline__ unsigned packbf(float a, float b) {
  return f2bf(a) | (f2bf(b) << 16);
}
__device__ __forceinline__ float bf_lo(unsigned u) { return __uint_as_float(u << 16); }
__device__ __forceinline__ float bf_hi(unsigned u) { return __uint_as_float(u & 0xFFFF0000u); }

// Fused: (a) convert 4 weight matrices to MFMA-fragment-ordered fp16
// (fragment fi=(t*4+chunk)*64+lane holds W[chunk*32+(lane>>4)*8+j][t*16+(lane&15)]),
// (b) count edges per dst segment, recording each edge's rank (atomic return).
__global__ __launch_bounds__(256) void prep(
    const float* __restrict__ W0, const float* __restrict__ W1,
    const float* __restrict__ W2, const float* __restrict__ W3,
    short* __restrict__ wfr,
    const int* __restrict__ ddst, const int* __restrict__ kedst, const int* __restrict__ ekdst,
    int* __restrict__ cnt_dir, int* __restrict__ cnt_ke, int* __restrict__ cnt_ek,
    unsigned short* __restrict__ rank_dir, unsigned short* __restrict__ rank_ke,
    unsigned short* __restrict__ rank_ek)
{
  int b = blockIdx.x;
  if (b < 32) {
    int wsel = b >> 3;
    const float* W = (wsel == 0) ? W0 : (wsel == 1) ? W1 : (wsel == 2) ? W2 : W3;
    int fi = (b & 7) * 256 + threadIdx.x;    // 0..2047
    int l = fi & 63, chunk = (fi >> 6) & 3, t = fi >> 8;
    int col = t * 16 + (l & 15);
    int kbase = chunk * 32 + (l >> 4) * 8;
    f16x8 hv;
#pragma unroll
    for (int j = 0; j < 8; ++j) hv[j] = (_Float16)W[(kbase + j) * 128 + col];
    ((f16x8*)(wfr + wsel * 16384))[fi] = hv;
    return;
  }
  int i = (b - 32) * 256 + threadIdx.x;
  if (i < E1N) {
    rank_dir[i] = (unsigned short)atomicAdd(&cnt_dir[ddst[i]], 1);
  } else if (i < E1N + E2N) {
    int e = i - E1N;
    int d = kedst[e];
    if (d >= IN_) rank_ke[e] = (unsigned short)atomicAdd(&cnt_ke[d - IN_], 1);
  } else {
    int e = i - E1N - E2N;
    int d = ekdst[e];
    if (d < IN_) rank_ek[e] = (unsigned short)atomicAdd(&cnt_ek[d], 1);
  }
}

// 3x MFMA gemms, fp16 2-term (W quantized fp16, emb split hi+lo fp16).
// 64 rows/block, 32 KB LDS. Epilogue: bf16 z rows + row dots -> ssrc/sdst.
__global__ __launch_bounds__(256, 4) void gemm3(
    const float* __restrict__ kn, const float* __restrict__ ex,
    const short* __restrict__ wfr,
    const float* __restrict__ a_dir, const float* __restrict__ a_ke, const float* __restrict__ a_ek,
    unsigned* __restrict__ zb_dir, unsigned* __restrict__ zb_ke, unsigned* __restrict__ zb_ek,
    float* __restrict__ sds, float* __restrict__ sdd,
    float* __restrict__ sks, float* __restrict__ skd,
    float* __restrict__ ses, float* __restrict__ sed)
{
  __shared__ short sW[16384];   // 32 KB fp16 fragments
  const int bid = blockIdx.x;
  const int tid = threadIdx.x;

  const float *h1, *h2, *avec;
  unsigned* zb;
  float *ssrc, *sdst;
  const short* wf;
  int split, rows, tile;
  if (bid < GB0) {
    tile = bid; rows = KN; split = KN; h1 = kn; h2 = kn;
    wf = wfr; avec = a_dir; zb = zb_dir; ssrc = sds; sdst = sdd;
  } else if (bid < GB0 + GB1) {
    tile = bid - GB0; rows = NN; split = IN_; h1 = ex; h2 = kn;
    wf = wfr + 16384; avec = a_ke; zb = zb_ke; ssrc = sks; sdst = skd;
  } else {
    tile = bid - GB0 - GB1; rows = NN; split = IN_; h1 = ex; h2 = kn;
    wf = wfr + 32768; avec = a_ek; zb = zb_ek; ssrc = ses; sdst = sed;
  }

  {
    const int4* gs = (const int4*)wf;
    int4* ls = (int4*)sW;
#pragma unroll
    for (int it = 0; it < 8; ++it) ls[it * 256 + tid] = gs[it * 256 + tid];
  }
  __syncthreads();

  const int lane = tid & 63;
  const int wv = tid >> 6;
  const int q = lane >> 4;
  const int m = lane & 15;
  const int r = tile * 64 + wv * 16 + m;
  const int rc = (r < rows) ? r : (rows - 1);
  const float* hp = (rc < split) ? (h1 + (size_t)rc * 128)
                                 : (h2 + (size_t)(rc - split) * 128);

  floatx4 acc[8];
#pragma unroll
  for (int t = 0; t < 8; ++t) { acc[t][0]=0.f; acc[t][1]=0.f; acc[t][2]=0.f; acc[t][3]=0.f; }

#pragma unroll
  for (int chunk = 0; chunk < 4; ++chunk) {
    float4 v0 = *(const float4*)(hp + chunk * 32 + q * 8);
    float4 v1 = *(const float4*)(hp + chunk * 32 + q * 8 + 4);
    float vs[8] = {v0.x, v0.y, v0.z, v0.w, v1.x, v1.y, v1.z, v1.w};
    f16x8 ahi, alo;
#pragma unroll
    for (int j = 0; j < 8; ++j) {
      _Float16 h = (_Float16)vs[j];
      ahi[j] = h;
      alo[j] = (_Float16)(vs[j] - (float)h);
    }
#pragma unroll
    for (int t = 0; t < 8; ++t) {
      f16x8 bh = ((const f16x8*)sW)[(t * 4 + chunk) * 64 + lane];
      acc[t] = __builtin_amdgcn_mfma_f32_16x16x32_f16(bh, ahi, acc[t], 0, 0, 0);
      acc[t] = __builtin_amdgcn_mfma_f32_16x16x32_f16(bh, alo, acc[t], 0, 0, 0);
    }
  }

  if (r < rows) {
    unsigned* zrow = zb + (size_t)r * 64;
#pragma unroll
    for (int t = 0; t < 8; ++t) {
      uint2 pk;
      pk.x = packbf(acc[t][0], acc[t][1]);
      pk.y = packbf(acc[t][2], acc[t][3]);
      *(uint2*)(zrow + t * 8 + q * 2) = pk;
    }
  }
  float d1 = 0.f, d2 = 0.f;
#pragma unroll
  for (int t = 0; t < 8; ++t) {
    float4 wa = *(const float4*)(avec + t * 16 + q * 4);
    float4 wb = *(const float4*)(avec + 128 + t * 16 + q * 4);
    d1 += acc[t][0] * wa.x + acc[t][1] * wa.y + acc[t][2] * wa.z + acc[t][3] * wa.w;
    d2 += acc[t][0] * wb.x + acc[t][1] * wb.y + acc[t][2] * wb.z + acc[t][3] * wb.w;
  }
  d1 += __shfl_xor(d1, 16, 64); d1 += __shfl_xor(d1, 32, 64);
  d2 += __shfl_xor(d2, 16, 64); d2 += __shfl_xor(d2, 32, 64);
  if (q == 0 && r < rows) { ssrc[r] = d1; sdst[r] = d2; }
}

// CSR allocation: wave shuffle-scan + 1 atomic/wave.
__global__ __launch_bounds__(256) void alloc_off(
    const int* __restrict__ cnt_dir, int* __restrict__ st_dir,
    const int* __restrict__ cnt_ke,  int* __restrict__ st_ke,
    const int* __restrict__ cnt_ek,  int* __restrict__ st_ek,
    int* __restrict__ totals)
{
  int b = blockIdx.x;
  const int* cnt; int* st; int* tot; int n, i0;
  if (b < 79)       { cnt = cnt_dir; st = st_dir; tot = totals + 0; n = KN;  i0 = b * 256; }
  else if (b < 158) { cnt = cnt_ke;  st = st_ke;  tot = totals + 1; n = KN;  i0 = (b - 79) * 256; }
  else              { cnt = cnt_ek;  st = st_ek;  tot = totals + 2; n = IN_; i0 = (b - 158) * 256; }
  int i = i0 + threadIdx.x;
  int lane = threadIdx.x & 63;
  int v = (i < n) ? cnt[i] : 0;
  int x = v;
#pragma unroll
  for (int o = 1; o < 64; o <<= 1) {
    int t = __shfl_up(x, o, 64);
    if (lane >= o) x += t;
  }
  int base = 0;
  if (lane == 63) base = atomicAdd(tot, x);
  base = __shfl(base, 63, 64);
  if (i < n) st[i] = base + x - v;
}

// atomic-free placement: pos = st[dst] + rank[e]; stores (src, score[src])
__global__ __launch_bounds__(256) void fill_edges(
    const int* __restrict__ dsrc, const int* __restrict__ ddst,
    const int* __restrict__ kesrc, const int* __restrict__ kedst,
    const int* __restrict__ eksrc, const int* __restrict__ ekdst,
    const unsigned short* __restrict__ rank_dir, const unsigned short* __restrict__ rank_ke,
    const unsigned short* __restrict__ rank_ek,
    const float* __restrict__ sds, const float* __restrict__ sks, const float* __restrict__ ses,
    const int* __restrict__ st_dir, int2* __restrict__ ep_dir,
    const int* __restrict__ st_ke,  int2* __restrict__ ep_ke,
    const int* __restrict__ st_ek,  int2* __restrict__ ep_ek)
{
  int i = blockIdx.x * 256 + threadIdx.x;
  if (i < E1N) {
    int d = ddst[i];
    int s = dsrc[i];
    ep_dir[st_dir[d] + rank_dir[i]] = make_int2(s, __float_as_int(sds[s]));
  } else if (i < E1N + E2N) {
    int e = i - E1N;
    int d = kedst[e];
    if (d >= IN_) {
      int s = kesrc[e];
      ep_ke[st_ke[d - IN_] + rank_ke[e]] = make_int2(s, __float_as_int(sks[s]));
    }
  } else {
    int e = i - E1N - E2N;
    int d = ekdst[e];
    if (d < IN_) {
      int s = eksrc[e];
      ep_ek[st_ek[d] + rank_ek[e]] = make_int2(s, __float_as_int(ses[s]));
    }
  }
}

// One wave per dst segment, single pass (m=0 softmax): accumulate exp-weighted
// bf16 rows + den, normalize after reduction. 4 groups x 16 lanes, 2x unroll.
__global__ __launch_bounds__(256) void gat_gather(
    const int* __restrict__ st_dir, const int* __restrict__ cnt_dir, const int2* __restrict__ ep_dir,
    const float* __restrict__ sdd, const unsigned* __restrict__ zb_dir, float* __restrict__ A,
    const int* __restrict__ st_ke, const int* __restrict__ cnt_ke, const int2* __restrict__ ep_ke,
    const float* __restrict__ skd, const unsigned* __restrict__ zb_ke, float* __restrict__ Bm,
    const int* __restrict__ st_ek, const int* __restrict__ cnt_ek, const int2* __restrict__ ep_ek,
    const float* __restrict__ sed, const unsigned* __restrict__ zb_ek, float* __restrict__ Cout)
{
  int w = (blockIdx.x * 256 + threadIdx.x) >> 6;
  int lane = threadIdx.x & 63;
  int gid = lane >> 4, gl = lane & 15;
  const int *st, *cn; const int2* ep;
  const float* sD;
  const unsigned* zb;
  float* out;
  int seg, node;
  if (w < KN)                { seg = w;          node = seg;       st = st_dir; cn = cnt_dir; ep = ep_dir; sD = sdd; zb = zb_dir; out = A; }
  else if (w < 2 * KN)       { seg = w - KN;     node = seg + IN_; st = st_ke;  cn = cnt_ke;  ep = ep_ke;  sD = skd; zb = zb_ke;  out = Bm; }
  else if (w < 2 * KN + IN_) { seg = w - 2 * KN; node = seg;       st = st_ek;  cn = cnt_ek;  ep = ep_ek;  sD = sed; zb = zb_ek;  out = Cout; }
  else return;

  int b = st[seg], e = b + cn[seg];
  float av[8];
#pragma unroll
  for (int k = 0; k < 8; ++k) av[k] = 0.f;
  float den = 0.f;

  if (e > b) {
    float sd = sD[node];
    int i = b + gid;
    for (; i + 4 < e; i += 8) {
      int2 p1 = ep[i], p2 = ep[i + 4];
      float x1 = __int_as_float(p1.y) + sd; x1 = (x1 > 0.f) ? x1 : 0.01f * x1;
      float x2 = __int_as_float(p2.y) + sd; x2 = (x2 > 0.f) ? x2 : 0.01f * x2;
      float w1 = __expf(x1), w2 = __expf(x2);
      uint4 za = *(const uint4*)(zb + (size_t)p1.x * 64 + gl * 4);
      uint4 zc = *(const uint4*)(zb + (size_t)p2.x * 64 + gl * 4);
      den += w1 + w2;
      av[0] += w1 * bf_lo(za.x); av[1] += w1 * bf_hi(za.x);
      av[2] += w1 * bf_lo(za.y); av[3] += w1 * bf_hi(za.y);
      av[4] += w1 * bf_lo(za.z); av[5] += w1 * bf_hi(za.z);
      av[6] += w1 * bf_lo(za.w); av[7] += w1 * bf_hi(za.w);
      av[0] += w2 * bf_lo(zc.x); av[1] += w2 * bf_hi(zc.x);
      av[2] += w2 * bf_lo(zc.y); av[3] += w2 * bf_hi(zc.y);
      av[4] += w2 * bf_lo(zc.z); av[5] += w2 * bf_hi(zc.z);
      av[6] += w2 * bf_lo(zc.w); av[7] += w2 * bf_hi(zc.w);
    }
    if (i < e) {
      int2 p1 = ep[i];
      float x1 = __int_as_float(p1.y) + sd; x1 = (x1 > 0.f) ? x1 : 0.01f * x1;
      float w1 = __expf(x1);
      uint4 za = *(const uint4*)(zb + (size_t)p1.x * 64 + gl * 4);
      den += w1;
      av[0] += w1 * bf_lo(za.x); av[1] += w1 * bf_hi(za.x);
      av[2] += w1 * bf_lo(za.y); av[3] += w1 * bf_hi(za.y);
      av[4] += w1 * bf_lo(za.z); av[5] += w1 * bf_hi(za.z);
      av[6] += w1 * bf_lo(za.w); av[7] += w1 * bf_hi(za.w);
    }
    den += __shfl_xor(den, 16, 64);
    den += __shfl_xor(den, 32, 64);
#pragma unroll
    for (int k = 0; k < 8; ++k) {
      av[k] += __shfl_xor(av[k], 16, 64);
      av[k] += __shfl_xor(av[k], 32, 64);
    }
    float inv = 1.f / den;
#pragma unroll
    for (int k = 0; k < 8; ++k) av[k] *= inv;
  }

  if (gid == 0) {
    float* op = out + (size_t)seg * 128 + gl * 8;
    *(float4*)op       = make_float4(av[0], av[1], av[2], av[3]);
    *(float4*)(op + 4) = make_float4(av[4], av[5], av[6], av[7]);
  }
}

// rel-gemm on Am and Bm rows (fp16 2-term) + tanh/w2 scores + softmax + combine.
__global__ __launch_bounds__(256, 2) void relgemm_combine(
    const float* __restrict__ Am, const float* __restrict__ Bm,
    const short* __restrict__ wfr_rel,
    const float* __restrict__ rb1, const float* __restrict__ rw2,
    float* __restrict__ out)
{
  __shared__ short sW[16384];
  const int tid = threadIdx.x;
  {
    const int4* gs = (const int4*)wfr_rel;
    int4* ls = (int4*)sW;
#pragma unroll
    for (int it = 0; it < 8; ++it) ls[it * 256 + tid] = gs[it * 256 + tid];
  }
  __syncthreads();

  const int lane = tid & 63;
  const int wv = tid >> 6;
  const int q = lane >> 4;
  const int m = lane & 15;
  const int r = blockIdx.x * 64 + wv * 16 + m;
  const int rc = (r < KN) ? r : (KN - 1);
  const float* hA = Am + (size_t)rc * 128;
  const float* hB = Bm + (size_t)rc * 128;

  floatx4 accA[8], accB[8];
#pragma unroll
  for (int t = 0; t < 8; ++t) {
    accA[t][0]=0.f; accA[t][1]=0.f; accA[t][2]=0.f; accA[t][3]=0.f;
    accB[t][0]=0.f; accB[t][1]=0.f; accB[t][2]=0.f; accB[t][3]=0.f;
  }

#pragma unroll
  for (int chunk = 0; chunk < 4; ++chunk) {
    float4 a0 = *(const float4*)(hA + chunk * 32 + q * 8);
    float4 a1 = *(const float4*)(hA + chunk * 32 + q * 8 + 4);
    float4 b0 = *(const float4*)(hB + chunk * 32 + q * 8);
    float4 b1 = *(const float4*)(hB + chunk * 32 + q * 8 + 4);
    float as[8] = {a0.x, a0.y, a0.z, a0.w, a1.x, a1.y, a1.z, a1.w};
    float bs[8] = {b0.x, b0.y, b0.z, b0.w, b1.x, b1.y, b1.z, b1.w};
    f16x8 ahiA, aloA, ahiB, aloB;
#pragma unroll
    for (int j = 0; j < 8; ++j) {
      _Float16 ha = (_Float16)as[j];
      ahiA[j] = ha; aloA[j] = (_Float16)(as[j] - (float)ha);
      _Float16 hb = (_Float16)bs[j];
      ahiB[j] = hb; aloB[j] = (_Float16)(bs[j] - (float)hb);
    }
#pragma unroll
    for (int t = 0; t < 8; ++t) {
      f16x8 bh = ((const f16x8*)sW)[(t * 4 + chunk) * 64 + lane];
      accA[t] = __builtin_amdgcn_mfma_f32_16x16x32_f16(bh, ahiA, accA[t], 0, 0, 0);
      accA[t] = __builtin_amdgcn_mfma_f32_16x16x32_f16(bh, aloA, accA[t], 0, 0, 0);
      accB[t] = __builtin_amdgcn_mfma_f32_16x16x32_f16(bh, ahiB, accB[t], 0, 0, 0);
      accB[t] = __builtin_amdgcn_mfma_f32_16x16x32_f16(bh, aloB, accB[t], 0, 0, 0);
    }
  }

  float p1 = 0.f, p2 = 0.f;
#pragma unroll
  for (int t = 0; t < 8; ++t) {
    float4 bb = *(const float4*)(rb1 + t * 16 + q * 4);
    float4 ww = *(const float4*)(rw2 + t * 16 + q * 4);
    p1 += tanhf(accA[t][0] + bb.x) * ww.x + tanhf(accA[t][1] + bb.y) * ww.y +
          tanhf(accA[t][2] + bb.z) * ww.z + tanhf(accA[t][3] + bb.w) * ww.w;
    p2 += tanhf(accB[t][0] + bb.x) * ww.x + tanhf(accB[t][1] + bb.y) * ww.y +
          tanhf(accB[t][2] + bb.z) * ww.z + tanhf(accB[t][3] + bb.w) * ww.w;
  }
  p1 += __shfl_xor(p1, 16, 64); p1 += __shfl_xor(p1, 32, 64);
  p2 += __shfl_xor(p2, 16, 64); p2 += __shfl_xor(p2, 32, 64);

  float mx = fmaxf(p1, p2);
  float e1 = __expf(p1 - mx), e2 = __expf(p2 - mx);
  float al = e1 / (e1 + e2), be = e2 / (e1 + e2);

  if (r < KN) {
#pragma unroll
    for (int t = 0; t < 8; ++t) {
      int col = t * 16 + q * 4;
      float4 avv = *(const float4*)(Am + (size_t)r * 128 + col);
      float4 bvv = *(const float4*)(Bm + (size_t)r * 128 + col);
      *(float4*)(out + (size_t)r * 128 + col) =
          make_float4(al * avv.x + be * bvv.x, al * avv.y + be * bvv.y,
                      al * avv.z + be * bvv.z, al * avv.w + be * bvv.w);
    }
  }
}

extern "C" void kernel_launch(void* const* d_in, const int* in_sizes, int n_in,
                              void* d_out, int out_size, void* d_ws, size_t ws_size,
                              hipStream_t stream) {
  const float* kn    = (const float*)d_in[0];
  const float* ex    = (const float*)d_in[1];
  const float* W_dir = (const float*)d_in[2];
  const float* a_dir = (const float*)d_in[3];
  const float* W_ke  = (const float*)d_in[4];
  const float* a_ke  = (const float*)d_in[5];
  const float* W_ek  = (const float*)d_in[6];
  const float* a_ek  = (const float*)d_in[7];
  const float* rW1   = (const float*)d_in[8];
  const float* rb1   = (const float*)d_in[9];
  const float* rw2   = (const float*)d_in[10];
  const int* dsrc    = (const int*)d_in[11];
  const int* ddst    = (const int*)d_in[12];
  const int* kesrc   = (const int*)d_in[13];
  const int* kedst   = (const int*)d_in[14];
  const int* eksrc   = (const int*)d_in[15];
  const int* ekdst   = (const int*)d_in[16];
  float* out = (float*)d_out;

  char* p = (char*)d_ws;
  auto alloc = [&](size_t bytes) {
    char* r = p;
    p += (bytes + 255) & ~(size_t)255;
    return r;
  };
  unsigned* zb_dir = (unsigned*)alloc((size_t)KN * 64 * 4);
  unsigned* zb_ke  = (unsigned*)alloc((size_t)NN * 64 * 4);
  unsigned* zb_ek  = (unsigned*)alloc((size_t)NN * 64 * 4);
  float* Am    = (float*)alloc((size_t)KN * 128 * 4);
  float* Bmat  = (float*)alloc((size_t)KN * 128 * 4);
  short* wfr   = (short*)alloc((size_t)4 * 16384 * 2);
  float* sds = (float*)alloc(KN * 4);
  float* sdd = (float*)alloc(KN * 4);
  float* sks = (float*)alloc(NN * 4);
  float* skd = (float*)alloc(NN * 4);
  float* ses = (float*)alloc(NN * 4);
  float* sed = (float*)alloc(NN * 4);
  int* cntblk  = (int*)alloc((size_t)(2 * KN + IN_ + 64) * 4);
  int* cnt_dir = cntblk;
  int* cnt_ke  = cntblk + KN;
  int* cnt_ek  = cntblk + 2 * KN;
  int* totals  = cntblk + 2 * KN + IN_;
  int* st_dir = (int*)alloc(KN * 4);
  int* st_ke  = (int*)alloc(KN * 4);
  int* st_ek  = (int*)alloc(IN_ * 4);
  unsigned short* rank_dir = (unsigned short*)alloc((size_t)E1N * 2);
  unsigned short* rank_ke  = (unsigned short*)alloc((size_t)E2N * 2);
  unsigned short* rank_ek  = (unsigned short*)alloc((size_t)E2N * 2);
  int2* ep_dir = (int2*)alloc((size_t)E1N * 8);
  int2* ep_ke  = (int2*)alloc((size_t)E2N * 8);
  int2* ep_ek  = (int2*)alloc((size_t)E2N * 8);

  hipMemsetAsync(cntblk, 0, (size_t)(2 * KN + IN_ + 64) * 4, stream);

  prep<<<32 + (E1N + 2 * E2N) / 256, 256, 0, stream>>>(
      W_dir, W_ke, W_ek, rW1, wfr,
      ddst, kedst, ekdst, cnt_dir, cnt_ke, cnt_ek,
      rank_dir, rank_ke, rank_ek);

  gemm3<<<GB0 + GB1 + GB2, 256, 0, stream>>>(
      kn, ex, wfr, a_dir, a_ke, a_ek,
      zb_dir, zb_ke, zb_ek,
      sds, sdd, sks, skd, ses, sed);

  alloc_off<<<354, 256, 0, stream>>>(cnt_dir, st_dir, cnt_ke, st_ke, cnt_ek, st_ek, totals);

  fill_edges<<<(E1N + 2 * E2N) / 256, 256, 0, stream>>>(
      dsrc, ddst, kesrc, kedst, eksrc, ekdst,
      rank_dir, rank_ke, rank_ek,
      sds, sks, ses,
      st_dir, ep_dir, st_ke, ep_ke, st_ek, ep_ek);

  gat_gather<<<(2 * KN + IN_) / 4, 256, 0, stream>>>(
      st_dir, cnt_dir, ep_dir, sdd, zb_dir, Am,
      st_ke,  cnt_ke,  ep_ke,  skd, zb_ke,  Bmat,
      st_ek,  cnt_ek,  ep_ek,  sed, zb_ek,  out + (size_t)KN * 128);

  relgemm_combine<<<313, 256, 0, stream>>>(Am, Bmat, wfr + 3 * 16384, rb1, rw2, out);
}